// Round 10
// baseline (3330.235 us; speedup 1.0000x reference)
//
#include <hip/hip_runtime.h>
#include <math.h>

typedef float f32;
typedef short short8 __attribute__((ext_vector_type(8)));
typedef float f32x4 __attribute__((ext_vector_type(4)));

#define TT 512
#define BB 64
#define DD 256
#define NN 48

// ===== workspace offsets (bytes). Peak ~153.0 MB =====
static const size_t OFF_EBF  = 0;                        // [32000][256] bf16
static const size_t OFF_PXF  = 16384000;                 // px packed [512][16][16][3][64] bf16
static const size_t OFF_PXB  = OFF_PXF + 50331648;
static const size_t OFF_HBF_F= OFF_PXB + 50331648;       // [512][64][256] bf16
static const size_t OFF_HBF_B= OFF_HBF_F + 16777216;
static const size_t OFF_WXTF = OFF_HBF_B + 16777216;     // [768][256] bf16
static const size_t OFF_WXTB = OFF_WXTF + 393216;
static const size_t OFF_WHTF = OFF_WXTB + 393216;        // [768][256] bf16 wh^T
static const size_t OFF_WHTB = OFF_WHTF + 393216;
static const size_t OFF_WQT  = OFF_WHTB + 393216;        // [256][512] bf16
static const size_t OFF_WKT  = OFF_WQT + 262144;
static const size_t OFF_WVT  = OFF_WKT + 262144;
static const size_t OFF_WTT  = OFF_WVT + 262144;         // [48][256] bf16
// end 152,985,600
// attn phase aliases the (dead) px arena [16,384,000 .. 117,047,296):
static const size_t OFF_QBF = OFF_PXF;                   // [64][512][256] bf16 (also ABF)
static const size_t OFF_KBF = OFF_QBF + 16777216;        // (also LG f32 after AV)
static const size_t OFF_VBF = OFF_KBF + 16777216;
static const size_t OFF_VT  = OFF_VBF + 16777216;        // [64][256][512] bf16
static const size_t OFF_SCB = OFF_VT  + 16777216;        // [64][512][512] bf16 (in-place SM)
static const size_t OFF_ABF = OFF_QBF;
static const size_t OFF_LG  = OFF_KBF;                   // [64][512][48] f32

__device__ __forceinline__ ushort f2bf(f32 f) {
  union { f32 f; unsigned u; } v; v.f = f;
  unsigned r = v.u + 0x7fffu + ((v.u >> 16) & 1u);   // RNE
  return (ushort)(r >> 16);
}
__device__ __forceinline__ f32 bf2f(ushort u) {
  union { unsigned u; f32 f; } v; v.u = ((unsigned)u) << 16; return v.f;
}
__device__ __forceinline__ f32 fsigmoid(f32 x) { return 1.f / (1.f + __expf(-x)); }
__device__ __forceinline__ f32 ftanh(f32 x) { return 1.f - 2.f / (__expf(2.f * x) + 1.f); }

// ---------------------------------------------------------------------------
// generic transpose+convert: in f32 [P][Q] -> out bf16 [Q][P], P = 1<<PL2
template <int PL2>
__global__ __launch_bounds__(256) void tconv_k(
    const f32* __restrict__ in, ushort* __restrict__ out, int total, int Q) {
  int o = blockIdx.x * 256 + threadIdx.x;
  if (o >= total) return;
  int q = o >> PL2, p = o & ((1 << PL2) - 1);
  out[o] = f2bf(in[(size_t)p * Q + q]);
}

// embed table f32 -> bf16
__global__ __launch_bounds__(256) void conv_embed_k(
    const f32* __restrict__ in, ushort* __restrict__ out, int n4) {
  int i = blockIdx.x * 256 + threadIdx.x;
  if (i >= n4) return;
  float4 v = ((const float4*)in)[i];
  ushort4 o;
  o.x = f2bf(v.x); o.y = f2bf(v.y); o.z = f2bf(v.z); o.w = f2bf(v.w);
  ((ushort4*)out)[i] = o;
}

// v transpose bf16: [64][512][256] -> [64][256][512]
__global__ __launch_bounds__(256) void tr_v_k(
    const ushort* __restrict__ in, ushort* __restrict__ out) {
  __shared__ ushort tile[32][33];
  int b = blockIdx.z;
  int s0 = blockIdx.x * 32, d0 = blockIdx.y * 32;
  int xc = threadIdx.x & 31, y0 = threadIdx.x >> 5;
  for (int yy = y0; yy < 32; yy += 8)
    tile[yy][xc] = in[((size_t)b * 512 + s0 + yy) * 256 + d0 + xc];
  __syncthreads();
  for (int yy = y0; yy < 32; yy += 8)
    out[((size_t)b * 256 + d0 + yy) * 512 + s0 + xc] = tile[xc][yy];
}

// ---------------------------------------------------------------------------
// bf16 MFMA GEMM: 128x128 block tile, BK=32, 256 thr (4 waves, 64x64 each).
enum { GM_PX = 0, GM_QKV = 1, GM_SC = 2, GM_AV = 3, GM_LG = 4 };

template <int MODE>
__global__ __launch_bounds__(256) void mgemm(
    const ushort* __restrict__ Aa, const ushort* __restrict__ Ab,
    const ushort* __restrict__ Bt,
    f32* __restrict__ Cf, ushort* __restrict__ Cb,
    const f32* __restrict__ bias, const int* __restrict__ xi,
    int Ndim, int K, int rev) {
  const int m0 = blockIdx.y * 128;
  const int n0 = blockIdx.x * 128;
  const int bz = blockIdx.z;
  const int tid = threadIdx.x;
  const int l = tid & 63, w = tid >> 6;
  const int wr = w >> 1, wc = w & 1;
  __shared__ __align__(16) short Al[128 * 40];
  __shared__ __align__(16) short Bl[128 * 40];
  f32x4 acc[4][4] = {};

  const int rowa = tid >> 1;
  const int kha = (tid & 1) * 16;
  const int rA = m0 + rowa;
  const ushort* aBase = nullptr;
  const ushort* aBase2 = nullptr;
  if constexpr (MODE == GM_PX) {
    int tg = rA >> 6, b = rA & 63;
    int ts = rev ? (511 - tg) : tg;
    aBase = Aa + (size_t)xi[b * 512 + ts] * 256;
  } else if constexpr (MODE == GM_QKV) {
    int bl = rA >> 9, t = rA & 511;
    aBase = Aa + ((size_t)(t * 64 + bl)) * 256;            // fwd half
    aBase2 = Ab + ((size_t)((511 - t) * 64 + bl)) * 256;   // bwd half
  } else if constexpr (MODE == GM_SC) {
    aBase = Aa + ((size_t)(bz * 512 + rA)) * 256;
  } else if constexpr (MODE == GM_AV) {
    aBase = Aa + ((size_t)(bz * 512 + rA)) * 512;
  } else {
    aBase = Aa + (size_t)rA * 256;
  }
  const int rowb = tid >> 1;
  const int khb = (tid & 1) * 16;
  int rowg = n0 + rowb;
  if constexpr (MODE == GM_SC) rowg += bz * 512;
  if constexpr (MODE == GM_AV) rowg += bz * 256;
  const ushort* bBase = Bt + (size_t)rowg * K;
  const bool bValid = (MODE != GM_LG) || (n0 + rowb < Ndim);

  for (int k0 = 0; k0 < K; k0 += 32) {
    {
      int kk = k0 + kha;
      const ushort* src;
      if constexpr (MODE == GM_QKV)
        src = (kk < 256) ? aBase + kk : aBase2 + (kk - 256);
      else
        src = aBase + kk;
      uint4 a0 = *(const uint4*)src;
      uint4 a1 = *(const uint4*)(src + 8);
      *(uint4*)&Al[rowa * 40 + kha] = a0;
      *(uint4*)&Al[rowa * 40 + kha + 8] = a1;
    }
    {
      uint4 v0 = make_uint4(0, 0, 0, 0), v1 = make_uint4(0, 0, 0, 0);
      if (bValid) {
        const ushort* src = bBase + k0 + khb;
        v0 = *(const uint4*)src;
        v1 = *(const uint4*)(src + 8);
      }
      *(uint4*)&Bl[rowb * 40 + khb] = v0;
      *(uint4*)&Bl[rowb * 40 + khb + 8] = v1;
    }
    __syncthreads();
    const int fr = l & 15, fg = l >> 4;
    short8 af[4], bfr[4];
#pragma unroll
    for (int mf = 0; mf < 4; ++mf)
      af[mf] = *(const short8*)&Al[(wr * 64 + mf * 16 + fr) * 40 + fg * 8];
#pragma unroll
    for (int nf = 0; nf < 4; ++nf)
      bfr[nf] = *(const short8*)&Bl[(wc * 64 + nf * 16 + fr) * 40 + fg * 8];
#pragma unroll
    for (int mf = 0; mf < 4; ++mf)
#pragma unroll
      for (int nf = 0; nf < 4; ++nf)
        acc[mf][nf] = __builtin_amdgcn_mfma_f32_16x16x32_bf16(
            af[mf], bfr[nf], acc[mf][nf], 0, 0, 0);
    __syncthreads();
  }

  const int fr = l & 15, fq = l >> 4;
#pragma unroll
  for (int mf = 0; mf < 4; ++mf) {
#pragma unroll
    for (int nf = 0; nf < 4; ++nf) {
      int col = n0 + wc * 64 + nf * 16 + fr;
      f32 bs = 0.f;
      if (bias && col < Ndim) bs = bias[col];
#pragma unroll
      for (int rg = 0; rg < 4; ++rg) {
        int row = m0 + wr * 64 + mf * 16 + fq * 4 + rg;
        f32 vv = acc[mf][nf][rg] + bs;
        if constexpr (MODE == GM_PX) {
          // packed px layout: [t][hc][gate][row]
          int tg = row >> 6, b = row & 63;
          int gate = col >> 8, hc = col & 255;
          Cb[(((size_t)tg * 256 + hc) * 3 + gate) * 64 + b] = f2bf(vv);
        } else if constexpr (MODE == GM_QKV)
          Cb[(size_t)row * 256 + col] = f2bf(vv);
        else if constexpr (MODE == GM_SC)
          Cb[((size_t)bz * 512 + row) * 512 + col] = f2bf(vv);
        else if constexpr (MODE == GM_AV)
          Cb[((size_t)bz * 512 + row) * 256 + col] = f2bf(vv);
        else {
          if (col < Ndim) Cf[(size_t)row * 48 + col] = vv;
        }
      }
    }
  }
}

// ---------------------------------------------------------------------------
// GRU scan v6: 8 WGs = 2 dir x 4 row-groups (16 rows), 512 thr (8 waves).
// px in named uint2 regs, k-block-major ldsH (conflict-free A-reads),
// Wh slab with (col&7)<<6 swizzle, f32 carry in named scalars. 1 barrier/step.
#define MFMA_B16 __builtin_amdgcn_mfma_f32_16x16x32_bf16

#define PXLOAD(T, P) {                                         \
  size_t tb_ = (size_t)(T) * 49152;                            \
  P##0 = *(const uint2*)(px + tb_ + off0);                     \
  P##1 = *(const uint2*)(px + tb_ + off0 + 64);                \
  P##2 = *(const uint2*)(px + tb_ + off0 + 128);               \
  P##3 = *(const uint2*)(px + tb_ + off1);                     \
  P##4 = *(const uint2*)(px + tb_ + off1 + 64);                \
  P##5 = *(const uint2*)(px + tb_ + off1 + 128);               \
}

#define GATE1(CT, RI, UZ, UR, UH, AZ, AR, AH, KB, BZ, BR, BH)  \
{                                                              \
  f32 zv_ = fsigmoid((AZ)[RI] + (BZ) + bf2f((ushort)(UZ)));    \
  f32 rv_ = fsigmoid((AR)[RI] + (BR) + bf2f((ushort)(UR)));    \
  f32 hc_ = ftanh(bf2f((ushort)(UH)) + rv_ * ((AH)[RI] + (BH)));\
  f32 hn_ = zv_ * h##CT##RI + (1.f - zv_) * hc_;               \
  h##CT##RI = hn_;                                             \
  *(ushort*)&dst_[(((KB) * 16) + fq * 4 + (RI)) * 16 + e2] = f2bf(hn_); \
}

#define STEP(T, BUF, PC, PN) {                                 \
  if ((T) + 1 < TT) PXLOAD((T) + 1, PN);                       \
  if ((T) > 0) {                                               \
    uint4 v_ = *(const uint4*)&ldsH[BUF][tid * 16];            \
    *(uint4*)&hseq[(((size_t)(T) - 1) * 64 + rowbase + (tid & 15)) * 256 + (tid >> 4) * 8] = v_; \
  }                                                            \
  uint2 q0_ = PC##0, q1_ = PC##1, q2_ = PC##2;                 \
  uint2 q3_ = PC##3, q4_ = PC##4, q5_ = PC##5;                 \
  f32x4 az0 = {}, az1 = {}, ar0 = {}, ar1 = {}, ah0 = {}, ah1 = {}; \
  _Pragma("unroll")                                            \
  for (int ks = 0; ks < 8; ++ks) {                             \
    short8 a_  = *(const short8*)&ldsH[BUF][((ks * 4 + fq) * 16 + fr) * 16]; \
    short8 w0_ = *(const short8*)&ldsWh[(ctb * 16 + fr) * 512 + ((ks * 64 + fq * 16) ^ ((fr & 7) << 6))]; \
    short8 w1_ = *(const short8*)&ldsWh[((ctb + 1) * 16 + fr) * 512 + ((ks * 64 + fq * 16) ^ ((fr & 7) << 6))]; \
    az0 = MFMA_B16(a_, wzv[0][ks], az0, 0, 0, 0);              \
    ar0 = MFMA_B16(a_, wrv[0][ks], ar0, 0, 0, 0);              \
    ah0 = MFMA_B16(a_, w0_, ah0, 0, 0, 0);                     \
    az1 = MFMA_B16(a_, wzv[1][ks], az1, 0, 0, 0);              \
    ar1 = MFMA_B16(a_, wrv[1][ks], ar1, 0, 0, 0);              \
    ah1 = MFMA_B16(a_, w1_, ah1, 0, 0, 0);                     \
  }                                                            \
  char* dst_ = ldsH[(BUF) ^ 1];                                \
  GATE1(0, 0, q0_.x,       q1_.x,       q2_.x,       az0, ar0, ah0, kb0, bhz0, bhr0, bhh0) \
  GATE1(0, 1, q0_.x >> 16, q1_.x >> 16, q2_.x >> 16, az0, ar0, ah0, kb0, bhz0, bhr0, bhh0) \
  GATE1(0, 2, q0_.y,       q1_.y,       q2_.y,       az0, ar0, ah0, kb0, bhz0, bhr0, bhh0) \
  GATE1(0, 3, q0_.y >> 16, q1_.y >> 16, q2_.y >> 16, az0, ar0, ah0, kb0, bhz0, bhr0, bhh0) \
  GATE1(1, 0, q3_.x,       q4_.x,       q5_.x,       az1, ar1, ah1, kb1, bhz1, bhr1, bhh1) \
  GATE1(1, 1, q3_.x >> 16, q4_.x >> 16, q5_.x >> 16, az1, ar1, ah1, kb1, bhz1, bhr1, bhh1) \
  GATE1(1, 2, q3_.y,       q4_.y,       q5_.y,       az1, ar1, ah1, kb1, bhz1, bhr1, bhh1) \
  GATE1(1, 3, q3_.y >> 16, q4_.y >> 16, q5_.y >> 16, az1, ar1, ah1, kb1, bhz1, bhr1, bhh1) \
  __syncthreads();                                             \
}

__global__ __launch_bounds__(512, 2) void gru_scan6(
    const ushort* __restrict__ pxf, const ushort* __restrict__ pxb,
    const ushort* __restrict__ whtf, const ushort* __restrict__ whtb,
    const f32* __restrict__ b_f, const f32* __restrict__ b_b,
    ushort* __restrict__ hfbf, ushort* __restrict__ hbbf) {
  const int dir = blockIdx.x >> 2;
  const int rg4 = blockIdx.x & 3;
  const int tid = threadIdx.x;
  const int w = tid >> 6, l = tid & 63;
  const int fr = l & 15, fq = l >> 4;
  const ushort* px  = dir ? pxb : pxf;
  const ushort* wht = dir ? whtb : whtf;
  const f32* bh = (dir ? b_b : b_f) + 768;
  ushort* hseq = dir ? hbbf : hfbf;

  __shared__ __align__(16) char ldsWh[131072];  // [col 0..255][512B k] swz (col&7)<<6
  __shared__ __align__(16) char ldsH[2][8192];  // [kblk 0..31][row 0..15][16B]

  // stage Wh (gate rows 512..767)
#pragma unroll
  for (int i = 0; i < 16; ++i) {
    int idx = i * 512 + tid;
    int col = idx >> 5, kc = idx & 31;
    uint4 v = *(const uint4*)&wht[(size_t)(512 + col) * 256 + kc * 8];
    *(uint4*)&ldsWh[col * 512 + ((kc * 16) ^ ((col & 7) << 6))] = v;
  }
  ((uint4*)ldsH[0])[tid] = make_uint4(0, 0, 0, 0);

  const int ctb = w * 2;
  short8 wzv[2][8], wrv[2][8];
#pragma unroll
  for (int ct = 0; ct < 2; ++ct) {
    int col = (ctb + ct) * 16 + fr;
#pragma unroll
    for (int ks = 0; ks < 8; ++ks) {
      wzv[ct][ks] = *(const short8*)&wht[(size_t)col * 256 + ks * 32 + fq * 8];
      wrv[ct][ks] = *(const short8*)&wht[(size_t)(256 + col) * 256 + ks * 32 + fq * 8];
    }
  }
  f32 bhz0, bhz1, bhr0, bhr1, bhh0, bhh1;
  {
    int c0 = ctb * 16 + fr, c1 = (ctb + 1) * 16 + fr;
    bhz0 = bh[c0]; bhz1 = bh[c1];
    bhr0 = bh[256 + c0]; bhr1 = bh[256 + c1];
    bhh0 = bh[512 + c0]; bhh1 = bh[512 + c1];
  }
  f32 h00 = 0.f, h01 = 0.f, h02 = 0.f, h03 = 0.f;
  f32 h10 = 0.f, h11 = 0.f, h12 = 0.f, h13 = 0.f;

  // px packed offsets (ushort units): [t][hc][gate][row]
  const int off0 = ((ctb + 0) * 16 + fr) * 192 + fq * 4;
  const int off1 = ((ctb + 1) * 16 + fr) * 192 + fq * 4;
  const int rowbase = rg4 * 16;
  const int kb0 = ctb * 2 + (fr >> 3);
  const int kb1 = kb0 + 2;
  const int e2 = (fr & 7) * 2;

  uint2 pA0, pA1, pA2, pA3, pA4, pA5;
  uint2 pB0, pB1, pB2, pB3, pB4, pB5;
  PXLOAD(0, pA);
  __syncthreads();

#pragma unroll 1
  for (int t2 = 0; t2 < TT; t2 += 2) {
    STEP(t2, 0, pA, pB);
    STEP(t2 + 1, 1, pB, pA);
  }
  // tail: hseq[511] = h(512) in ldsH[0]
  {
    uint4 v = *(const uint4*)&ldsH[0][tid * 16];
    *(uint4*)&hseq[((size_t)511 * 64 + rowbase + (tid & 15)) * 256 + (tid >> 4) * 8] = v;
  }
}

// ---------------------------------------------------------------------------
// in-place row softmax over 512 bf16, one block per row
__global__ __launch_bounds__(256) void softmax_ip(ushort* __restrict__ p) {
  size_t row = blockIdx.x;
  uint* pr = (uint*)(p + row * 512);
  int tid = threadIdx.x;
  uint u = pr[tid];
  f32 v0 = bf2f((ushort)(u & 0xffff)), v1 = bf2f((ushort)(u >> 16));
  f32 m = fmaxf(v0, v1);
  for (int off = 32; off; off >>= 1) m = fmaxf(m, __shfl_xor(m, off));
  __shared__ f32 red[4];
  __shared__ f32 red2[4];
  if ((tid & 63) == 0) red[tid >> 6] = m;
  __syncthreads();
  m = fmaxf(fmaxf(red[0], red[1]), fmaxf(red[2], red[3]));
  f32 e0 = __expf(v0 - m), e1 = __expf(v1 - m);
  f32 s = e0 + e1;
  for (int off = 32; off; off >>= 1) s += __shfl_xor(s, off);
  if ((tid & 63) == 0) red2[tid >> 6] = s;
  __syncthreads();
  s = red2[0] + red2[1] + red2[2] + red2[3];
  f32 inv = 1.f / s;
  pr[tid] = (uint)f2bf(e0 * inv) | ((uint)f2bf(e1 * inv) << 16);
}

// ---------------------------------------------------------------------------
// CRF log-likelihood, one block (1 wave) per batch element.
__global__ __launch_bounds__(64) void crf_ll_k(
    const f32* __restrict__ logits, const int* __restrict__ y,
    const int* __restrict__ seq_len, const f32* __restrict__ trans,
    f32* __restrict__ out) {
  const int b = blockIdx.x, tid = threadIdx.x;
  __shared__ f32 tr[NN * NN];
  for (int i = tid; i < NN * NN; i += 64) tr[i] = trans[i];
  const f32* em = logits + (size_t)b * TT * NN;
  const int L = seq_len[b];
  const bool act = tid < NN;
  f32 Ecol[NN];
#pragma unroll
  for (int i = 0; i < NN; ++i)
    Ecol[i] = act ? __expf(trans[i * NN + tid]) : 0.f;
  f32 alpha = act ? em[tid] : -1e30f;
  __syncthreads();
  for (int t = 1; t < L; ++t) {
    f32 m = alpha;
    for (int off = 32; off; off >>= 1) m = fmaxf(m, __shfl_xor(m, off));
    f32 e = __expf(alpha - m);
    f32 s = 0.f;
#pragma unroll
    for (int i = 0; i < NN; ++i) s += __shfl(e, i) * Ecol[i];
    if (act) alpha = m + __logf(s) + em[t * NN + tid];
  }
  f32 us = 0.f, ts = 0.f;
  for (int t = tid; t < TT; t += 64) {
    if (t < L) {
      us += em[t * NN + y[b * TT + t]];
      if (t >= 1) ts += tr[y[b * TT + t - 1] * NN + y[b * TT + t]];
    }
  }
  for (int off = 32; off; off >>= 1) { us += __shfl_xor(us, off); ts += __shfl_xor(ts, off); }
  f32 m = alpha;
  for (int off = 32; off; off >>= 1) m = fmaxf(m, __shfl_xor(m, off));
  f32 e = __expf(alpha - m);
  f32 s = e;
  for (int off = 32; off; off >>= 1) s += __shfl_xor(s, off);
  if (tid == 0) out[(size_t)BB * TT + b] = us + ts - (m + __logf(s));
}

// CRF Viterbi decode, one block (1 wave) per batch element
__global__ __launch_bounds__(64) void crf_decode_k(
    const f32* __restrict__ logits, const int* __restrict__ seq_len,
    const f32* __restrict__ trans, f32* __restrict__ out) {
  const int b = blockIdx.x, tid = threadIdx.x;
  __shared__ f32 tr[NN][NN];
  __shared__ f32 al[2][NN];
  __shared__ unsigned char bp[TT - 1][NN];
  __shared__ unsigned char pr[TT];
  for (int i = tid; i < NN * NN; i += 64) tr[i / NN][i % NN] = trans[i];
  const f32* em = logits + (size_t)b * TT * NN;
  const int L = seq_len[b];
  if (tid < NN) al[0][tid] = em[tid];
  __syncthreads();
  int cur = 0;
  for (int t = 1; t < TT; ++t) {
    if (tid < NN) {
      if (t < L) {
        f32 m = -1e30f; int arg = 0;
        for (int i = 0; i < NN; ++i) {
          f32 v = al[cur][i] + tr[i][tid];
          if (v > m) { m = v; arg = i; }
        }
        al[cur ^ 1][tid] = m + em[t * NN + tid];
        bp[t - 1][tid] = (unsigned char)arg;
      } else {
        al[cur ^ 1][tid] = al[cur][tid];
        bp[t - 1][tid] = (unsigned char)tid;
      }
    }
    __syncthreads();
    cur ^= 1;
  }
  if (tid == 0) {
    f32 m = -1e30f; int last = 0;
    for (int i = 0; i < NN; ++i)
      if (al[cur][i] > m) { m = al[cur][i]; last = i; }
    int tag = last;
    for (int t = TT - 2; t >= 0; --t) { pr[t + 1] = (unsigned char)tag; tag = bp[t][tag]; }
    pr[0] = (unsigned char)tag;
  }
  __syncthreads();
  for (int t = tid; t < TT; t += 64)
    out[(size_t)b * TT + t] = (f32)pr[t];
}

// ---------------------------------------------------------------------------
extern "C" void kernel_launch(void* const* d_in, const int* in_sizes, int n_in,
                              void* d_out, int out_size, void* d_ws, size_t ws_size,
                              hipStream_t stream) {
  const int* x       = (const int*)d_in[0];
  const int* y       = (const int*)d_in[1];
  const int* seq_len = (const int*)d_in[2];
  const f32* embed   = (const f32*)d_in[3];
  const f32* wx_f    = (const f32*)d_in[4];
  const f32* wh_f    = (const f32*)d_in[5];
  const f32* b_f     = (const f32*)d_in[6];
  const f32* wx_b    = (const f32*)d_in[7];
  const f32* wh_b    = (const f32*)d_in[8];
  const f32* b_b     = (const f32*)d_in[9];
  const f32* wq      = (const f32*)d_in[10];
  const f32* bq      = (const f32*)d_in[11];
  const f32* wk      = (const f32*)d_in[12];
  const f32* bk      = (const f32*)d_in[13];
  const f32* wv      = (const f32*)d_in[14];
  const f32* bv      = (const f32*)d_in[15];
  const f32* wt      = (const f32*)d_in[16];
  const f32* bt      = (const f32*)d_in[17];
  const f32* trans   = (const f32*)d_in[18];
  f32* out = (f32*)d_out;

  char* ws = (char*)d_ws;
  ushort* ebf  = (ushort*)(ws + OFF_EBF);
  ushort* pxfb = (ushort*)(ws + OFF_PXF);
  ushort* pxbb = (ushort*)(ws + OFF_PXB);
  ushort* hfbf = (ushort*)(ws + OFF_HBF_F);
  ushort* hbbf = (ushort*)(ws + OFF_HBF_B);
  ushort* wxtf = (ushort*)(ws + OFF_WXTF);
  ushort* wxtb = (ushort*)(ws + OFF_WXTB);
  ushort* whtf = (ushort*)(ws + OFF_WHTF);
  ushort* whtb = (ushort*)(ws + OFF_WHTB);
  ushort* wqt  = (ushort*)(ws + OFF_WQT);
  ushort* wkt  = (ushort*)(ws + OFF_WKT);
  ushort* wvt  = (ushort*)(ws + OFF_WVT);
  ushort* wtt  = (ushort*)(ws + OFF_WTT);
  ushort* qbf = (ushort*)(ws + OFF_QBF);
  ushort* kbf = (ushort*)(ws + OFF_KBF);
  ushort* vbf = (ushort*)(ws + OFF_VBF);
  ushort* vT  = (ushort*)(ws + OFF_VT);
  ushort* scb = (ushort*)(ws + OFF_SCB);
  ushort* abf = (ushort*)(ws + OFF_ABF);
  f32*    lg  = (f32*)(ws + OFF_LG);

  // ---- setup converts ----
  conv_embed_k<<<8000, 256, 0, stream>>>(embed, ebf, 2048000);
  tconv_k<8><<<768, 256, 0, stream>>>(wx_f, wxtf, 196608, 768);
  tconv_k<8><<<768, 256, 0, stream>>>(wx_b, wxtb, 196608, 768);
  tconv_k<8><<<768, 256, 0, stream>>>(wh_f, whtf, 196608, 768);
  tconv_k<8><<<768, 256, 0, stream>>>(wh_b, whtb, 196608, 768);
  tconv_k<9><<<512, 256, 0, stream>>>(wq, wqt, 131072, 256);
  tconv_k<9><<<512, 256, 0, stream>>>(wk, wkt, 131072, 256);
  tconv_k<9><<<512, 256, 0, stream>>>(wv, wvt, 131072, 256);
  tconv_k<8><<<48, 256, 0, stream>>>(wt, wtt, 12288, 48);

  // ---- px (both dirs, packed layout), then pipelined MFMA scan ----
  mgemm<GM_PX><<<dim3(6, 256), 256, 0, stream>>>(
      ebf, nullptr, wxtf, nullptr, pxfb, b_f, x, 768, 256, 0);
  mgemm<GM_PX><<<dim3(6, 256), 256, 0, stream>>>(
      ebf, nullptr, wxtb, nullptr, pxbb, b_b, x, 768, 256, 1);
  gru_scan6<<<8, 512, 0, stream>>>(pxfb, pxbb, whtf, whtb, b_f, b_b, hfbf, hbbf);

  // ---- attention + logits, single pass over all 64 batches ----
  mgemm<GM_QKV><<<dim3(2, 256), 256, 0, stream>>>(
      hfbf, hbbf, wqt, nullptr, qbf, bq, nullptr, 256, 512, 0);
  mgemm<GM_QKV><<<dim3(2, 256), 256, 0, stream>>>(
      hfbf, hbbf, wkt, nullptr, kbf, bk, nullptr, 256, 512, 0);
  mgemm<GM_QKV><<<dim3(2, 256), 256, 0, stream>>>(
      hfbf, hbbf, wvt, nullptr, vbf, bv, nullptr, 256, 512, 0);
  tr_v_k<<<dim3(16, 8, 64), 256, 0, stream>>>(vbf, vT);
  mgemm<GM_SC><<<dim3(4, 4, 64), 256, 0, stream>>>(
      qbf, nullptr, kbf, nullptr, scb, nullptr, nullptr, 512, 256, 0);
  softmax_ip<<<BB * TT, 256, 0, stream>>>(scb);
  mgemm<GM_AV><<<dim3(2, 4, 64), 256, 0, stream>>>(
      scb, nullptr, vT, nullptr, abf, nullptr, nullptr, 256, 512, 0);
  mgemm<GM_LG><<<dim3(1, 256), 256, 0, stream>>>(
      abf, nullptr, wtt, lg, nullptr, bt, nullptr, 48, 256, 0);

  // ---- CRF ----
  crf_ll_k<<<BB, 64, 0, stream>>>(lg, y, seq_len, trans, out);
  crf_decode_k<<<BB, 64, 0, stream>>>(lg, seq_len, trans, out);
}

// Round 12
// 3147.028 us; speedup vs baseline: 1.0582x; 1.0582x over previous
//
#include <hip/hip_runtime.h>
#include <math.h>

typedef float f32;
typedef short short8 __attribute__((ext_vector_type(8)));
typedef float f32x4 __attribute__((ext_vector_type(4)));

#define TT 512
#define BB 64
#define DD 256
#define NN 48

// ===== workspace offsets (bytes). Peak ~153.0 MB =====
static const size_t OFF_EBF  = 0;                        // [32000][256] bf16
static const size_t OFF_PXF  = 16384000;                 // px packed [512][16][16][3][64] bf16
static const size_t OFF_PXB  = OFF_PXF + 50331648;
static const size_t OFF_HBF_F= OFF_PXB + 50331648;       // [512][64][256] bf16
static const size_t OFF_HBF_B= OFF_HBF_F + 16777216;
static const size_t OFF_WXTF = OFF_HBF_B + 16777216;     // [768][256] bf16
static const size_t OFF_WXTB = OFF_WXTF + 393216;
static const size_t OFF_WHTF = OFF_WXTB + 393216;        // [768][256] bf16 wh^T
static const size_t OFF_WHTB = OFF_WHTF + 393216;
static const size_t OFF_WQT  = OFF_WHTB + 393216;        // [256][512] bf16
static const size_t OFF_WKT  = OFF_WQT + 262144;
static const size_t OFF_WVT  = OFF_WKT + 262144;
static const size_t OFF_WTT  = OFF_WVT + 262144;         // [48][256] bf16
// end 152,985,600
// attn phase aliases the (dead) px arena [16,384,000 .. 117,047,296):
static const size_t OFF_QBF = OFF_PXF;                   // [64][512][256] bf16 (also ABF)
static const size_t OFF_KBF = OFF_QBF + 16777216;        // (also LG f32 after AV)
static const size_t OFF_VBF = OFF_KBF + 16777216;
static const size_t OFF_VT  = OFF_VBF + 16777216;        // [64][256][512] bf16
static const size_t OFF_SCB = OFF_VT  + 16777216;        // [64][512][512] bf16 (in-place SM)
static const size_t OFF_ABF = OFF_QBF;
static const size_t OFF_LG  = OFF_KBF;                   // [64][512][48] f32

__device__ __forceinline__ ushort f2bf(f32 f) {
  union { f32 f; unsigned u; } v; v.f = f;
  unsigned r = v.u + 0x7fffu + ((v.u >> 16) & 1u);   // RNE
  return (ushort)(r >> 16);
}
__device__ __forceinline__ f32 bf2f(ushort u) {
  union { unsigned u; f32 f; } v; v.u = ((unsigned)u) << 16; return v.f;
}
__device__ __forceinline__ f32 fsigmoid(f32 x) { return 1.f / (1.f + __expf(-x)); }
__device__ __forceinline__ f32 ftanh(f32 x) { return 1.f - 2.f / (__expf(2.f * x) + 1.f); }

// ---------------------------------------------------------------------------
// generic transpose+convert: in f32 [P][Q] -> out bf16 [Q][P], P = 1<<PL2
template <int PL2>
__global__ __launch_bounds__(256) void tconv_k(
    const f32* __restrict__ in, ushort* __restrict__ out, int total, int Q) {
  int o = blockIdx.x * 256 + threadIdx.x;
  if (o >= total) return;
  int q = o >> PL2, p = o & ((1 << PL2) - 1);
  out[o] = f2bf(in[(size_t)p * Q + q]);
}

// embed table f32 -> bf16
__global__ __launch_bounds__(256) void conv_embed_k(
    const f32* __restrict__ in, ushort* __restrict__ out, int n4) {
  int i = blockIdx.x * 256 + threadIdx.x;
  if (i >= n4) return;
  float4 v = ((const float4*)in)[i];
  ushort4 o;
  o.x = f2bf(v.x); o.y = f2bf(v.y); o.z = f2bf(v.z); o.w = f2bf(v.w);
  ((ushort4*)out)[i] = o;
}

// v transpose bf16: [64][512][256] -> [64][256][512]
__global__ __launch_bounds__(256) void tr_v_k(
    const ushort* __restrict__ in, ushort* __restrict__ out) {
  __shared__ ushort tile[32][33];
  int b = blockIdx.z;
  int s0 = blockIdx.x * 32, d0 = blockIdx.y * 32;
  int xc = threadIdx.x & 31, y0 = threadIdx.x >> 5;
  for (int yy = y0; yy < 32; yy += 8)
    tile[yy][xc] = in[((size_t)b * 512 + s0 + yy) * 256 + d0 + xc];
  __syncthreads();
  for (int yy = y0; yy < 32; yy += 8)
    out[((size_t)b * 256 + d0 + yy) * 512 + s0 + xc] = tile[xc][yy];
}

// ---------------------------------------------------------------------------
// bf16 MFMA GEMM: 128x128 block tile, BK=32, 256 thr (4 waves, 64x64 each).
enum { GM_PX = 0, GM_QKV = 1, GM_SC = 2, GM_AV = 3, GM_LG = 4 };

template <int MODE>
__global__ __launch_bounds__(256) void mgemm(
    const ushort* __restrict__ Aa, const ushort* __restrict__ Ab,
    const ushort* __restrict__ Bt,
    f32* __restrict__ Cf, ushort* __restrict__ Cb,
    const f32* __restrict__ bias, const int* __restrict__ xi,
    int Ndim, int K, int rev) {
  const int m0 = blockIdx.y * 128;
  const int n0 = blockIdx.x * 128;
  const int bz = blockIdx.z;
  const int tid = threadIdx.x;
  const int l = tid & 63, w = tid >> 6;
  const int wr = w >> 1, wc = w & 1;
  __shared__ __align__(16) short Al[128 * 40];
  __shared__ __align__(16) short Bl[128 * 40];
  f32x4 acc[4][4] = {};

  const int rowa = tid >> 1;
  const int kha = (tid & 1) * 16;
  const int rA = m0 + rowa;
  const ushort* aBase = nullptr;
  const ushort* aBase2 = nullptr;
  if constexpr (MODE == GM_PX) {
    int tg = rA >> 6, b = rA & 63;
    int ts = rev ? (511 - tg) : tg;
    aBase = Aa + (size_t)xi[b * 512 + ts] * 256;
  } else if constexpr (MODE == GM_QKV) {
    int bl = rA >> 9, t = rA & 511;
    aBase = Aa + ((size_t)(t * 64 + bl)) * 256;            // fwd half
    aBase2 = Ab + ((size_t)((511 - t) * 64 + bl)) * 256;   // bwd half
  } else if constexpr (MODE == GM_SC) {
    aBase = Aa + ((size_t)(bz * 512 + rA)) * 256;
  } else if constexpr (MODE == GM_AV) {
    aBase = Aa + ((size_t)(bz * 512 + rA)) * 512;
  } else {
    aBase = Aa + (size_t)rA * 256;
  }
  const int rowb = tid >> 1;
  const int khb = (tid & 1) * 16;
  int rowg = n0 + rowb;
  if constexpr (MODE == GM_SC) rowg += bz * 512;
  if constexpr (MODE == GM_AV) rowg += bz * 256;
  const ushort* bBase = Bt + (size_t)rowg * K;
  const bool bValid = (MODE != GM_LG) || (n0 + rowb < Ndim);

  for (int k0 = 0; k0 < K; k0 += 32) {
    {
      int kk = k0 + kha;
      const ushort* src;
      if constexpr (MODE == GM_QKV)
        src = (kk < 256) ? aBase + kk : aBase2 + (kk - 256);
      else
        src = aBase + kk;
      uint4 a0 = *(const uint4*)src;
      uint4 a1 = *(const uint4*)(src + 8);
      *(uint4*)&Al[rowa * 40 + kha] = a0;
      *(uint4*)&Al[rowa * 40 + kha + 8] = a1;
    }
    {
      uint4 v0 = make_uint4(0, 0, 0, 0), v1 = make_uint4(0, 0, 0, 0);
      if (bValid) {
        const ushort* src = bBase + k0 + khb;
        v0 = *(const uint4*)src;
        v1 = *(const uint4*)(src + 8);
      }
      *(uint4*)&Bl[rowb * 40 + khb] = v0;
      *(uint4*)&Bl[rowb * 40 + khb + 8] = v1;
    }
    __syncthreads();
    const int fr = l & 15, fg = l >> 4;
    short8 af[4], bfr[4];
#pragma unroll
    for (int mf = 0; mf < 4; ++mf)
      af[mf] = *(const short8*)&Al[(wr * 64 + mf * 16 + fr) * 40 + fg * 8];
#pragma unroll
    for (int nf = 0; nf < 4; ++nf)
      bfr[nf] = *(const short8*)&Bl[(wc * 64 + nf * 16 + fr) * 40 + fg * 8];
#pragma unroll
    for (int mf = 0; mf < 4; ++mf)
#pragma unroll
      for (int nf = 0; nf < 4; ++nf)
        acc[mf][nf] = __builtin_amdgcn_mfma_f32_16x16x32_bf16(
            af[mf], bfr[nf], acc[mf][nf], 0, 0, 0);
    __syncthreads();
  }

  const int fr = l & 15, fq = l >> 4;
#pragma unroll
  for (int mf = 0; mf < 4; ++mf) {
#pragma unroll
    for (int nf = 0; nf < 4; ++nf) {
      int col = n0 + wc * 64 + nf * 16 + fr;
      f32 bs = 0.f;
      if (bias && col < Ndim) bs = bias[col];
#pragma unroll
      for (int rg = 0; rg < 4; ++rg) {
        int row = m0 + wr * 64 + mf * 16 + fq * 4 + rg;
        f32 vv = acc[mf][nf][rg] + bs;
        if constexpr (MODE == GM_PX) {
          // packed px layout: [t][hc][gate][row]
          int tg = row >> 6, b = row & 63;
          int gate = col >> 8, hc = col & 255;
          Cb[(((size_t)tg * 256 + hc) * 3 + gate) * 64 + b] = f2bf(vv);
        } else if constexpr (MODE == GM_QKV)
          Cb[(size_t)row * 256 + col] = f2bf(vv);
        else if constexpr (MODE == GM_SC)
          Cb[((size_t)bz * 512 + row) * 512 + col] = f2bf(vv);
        else if constexpr (MODE == GM_AV)
          Cb[((size_t)bz * 512 + row) * 256 + col] = f2bf(vv);
        else {
          if (col < Ndim) Cf[(size_t)row * 48 + col] = vv;
        }
      }
    }
  }
}

// ---------------------------------------------------------------------------
// GRU scan v7: 8 WGs = 2 dir x 4 row-groups (16 rows), 512 thr (8 waves).
// z/r weights PINNED into registers (per-dword asm "+v" defeats remat),
// Wh in swizzled LDS, k-block-major ldsH, f32 carry in named scalars,
// packed px in named uint2 regs. 1 barrier/step.
#define MFMA_B16 __builtin_amdgcn_mfma_f32_16x16x32_bf16

#define PXLOAD(T, P) {                                         \
  size_t tb_ = (size_t)(T) * 49152;                            \
  P##0 = *(const uint2*)(px + tb_ + off0);                     \
  P##1 = *(const uint2*)(px + tb_ + off0 + 64);                \
  P##2 = *(const uint2*)(px + tb_ + off0 + 128);               \
  P##3 = *(const uint2*)(px + tb_ + off1);                     \
  P##4 = *(const uint2*)(px + tb_ + off1 + 64);                \
  P##5 = *(const uint2*)(px + tb_ + off1 + 128);               \
}

#define GATE1(CT, RI, UZ, UR, UH, AZ, AR, AH, KB, BZ, BR, BH)  \
{                                                              \
  f32 zv_ = fsigmoid((AZ)[RI] + (BZ) + bf2f((ushort)(UZ)));    \
  f32 rv_ = fsigmoid((AR)[RI] + (BR) + bf2f((ushort)(UR)));    \
  f32 hc_ = ftanh(bf2f((ushort)(UH)) + rv_ * ((AH)[RI] + (BH)));\
  f32 hn_ = zv_ * h##CT##RI + (1.f - zv_) * hc_;               \
  h##CT##RI = hn_;                                             \
  *(ushort*)&dst_[(((KB) * 16) + fq * 4 + (RI)) * 16 + e2] = f2bf(hn_); \
}

#define STEP(T, BUF, PC, PN) {                                 \
  if ((T) + 1 < TT) PXLOAD((T) + 1, PN);                       \
  if ((T) > 0) {                                               \
    uint4 v_ = *(const uint4*)&ldsH[BUF][tid * 16];            \
    *(uint4*)&hseq[(((size_t)(T) - 1) * 64 + rowbase + (tid & 15)) * 256 + (tid >> 4) * 8] = v_; \
  }                                                            \
  uint2 q0_ = PC##0, q1_ = PC##1, q2_ = PC##2;                 \
  uint2 q3_ = PC##3, q4_ = PC##4, q5_ = PC##5;                 \
  f32x4 az0 = {}, az1 = {}, ar0 = {}, ar1 = {}, ah0 = {}, ah1 = {}; \
  _Pragma("unroll")                                            \
  for (int ks = 0; ks < 8; ++ks) {                             \
    short8 a_  = *(const short8*)&ldsH[BUF][((ks * 4 + fq) * 16 + fr) * 16]; \
    short8 w0_ = *(const short8*)&ldsWh[(ctb * 16 + fr) * 512 + ((ks * 64 + fq * 16) ^ ((fr & 7) << 6))]; \
    short8 w1_ = *(const short8*)&ldsWh[((ctb + 1) * 16 + fr) * 512 + ((ks * 64 + fq * 16) ^ ((fr & 7) << 6))]; \
    az0 = MFMA_B16(a_, __builtin_bit_cast(short8, wzu[0][ks]), az0, 0, 0, 0); \
    ar0 = MFMA_B16(a_, __builtin_bit_cast(short8, wru[0][ks]), ar0, 0, 0, 0); \
    ah0 = MFMA_B16(a_, w0_, ah0, 0, 0, 0);                     \
    az1 = MFMA_B16(a_, __builtin_bit_cast(short8, wzu[1][ks]), az1, 0, 0, 0); \
    ar1 = MFMA_B16(a_, __builtin_bit_cast(short8, wru[1][ks]), ar1, 0, 0, 0); \
    ah1 = MFMA_B16(a_, w1_, ah1, 0, 0, 0);                     \
  }                                                            \
  char* dst_ = ldsH[(BUF) ^ 1];                                \
  GATE1(0, 0, q0_.x,       q1_.x,       q2_.x,       az0, ar0, ah0, kb0, bhz0, bhr0, bhh0) \
  GATE1(0, 1, q0_.x >> 16, q1_.x >> 16, q2_.x >> 16, az0, ar0, ah0, kb0, bhz0, bhr0, bhh0) \
  GATE1(0, 2, q0_.y,       q1_.y,       q2_.y,       az0, ar0, ah0, kb0, bhz0, bhr0, bhh0) \
  GATE1(0, 3, q0_.y >> 16, q1_.y >> 16, q2_.y >> 16, az0, ar0, ah0, kb0, bhz0, bhr0, bhh0) \
  GATE1(1, 0, q3_.x,       q4_.x,       q5_.x,       az1, ar1, ah1, kb1, bhz1, bhr1, bhh1) \
  GATE1(1, 1, q3_.x >> 16, q4_.x >> 16, q5_.x >> 16, az1, ar1, ah1, kb1, bhz1, bhr1, bhh1) \
  GATE1(1, 2, q3_.y,       q4_.y,       q5_.y,       az1, ar1, ah1, kb1, bhz1, bhr1, bhh1) \
  GATE1(1, 3, q3_.y >> 16, q4_.y >> 16, q5_.y >> 16, az1, ar1, ah1, kb1, bhz1, bhr1, bhh1) \
  __syncthreads();                                             \
}

__global__ __launch_bounds__(512, 1) void gru_scan7(
    const ushort* __restrict__ pxf, const ushort* __restrict__ pxb,
    const ushort* __restrict__ whtf, const ushort* __restrict__ whtb,
    const f32* __restrict__ b_f, const f32* __restrict__ b_b,
    ushort* __restrict__ hfbf, ushort* __restrict__ hbbf) {
  const int dir = blockIdx.x >> 2;
  const int rg4 = blockIdx.x & 3;
  const int tid = threadIdx.x;
  const int w = tid >> 6, l = tid & 63;
  const int fr = l & 15, fq = l >> 4;
  const ushort* px  = dir ? pxb : pxf;
  const ushort* wht = dir ? whtb : whtf;
  const f32* bh = (dir ? b_b : b_f) + 768;
  ushort* hseq = dir ? hbbf : hfbf;

  __shared__ __align__(16) char ldsWh[131072];  // [col 0..255][512B k] swz (col&7)<<6
  __shared__ __align__(16) char ldsH[2][8192];  // [kblk 0..31][row 0..15][16B]

  // stage Wh (gate rows 512..767)
#pragma unroll
  for (int i = 0; i < 16; ++i) {
    int idx = i * 512 + tid;
    int col = idx >> 5, kc = idx & 31;
    uint4 v = *(const uint4*)&wht[(size_t)(512 + col) * 256 + kc * 8];
    *(uint4*)&ldsWh[col * 512 + ((kc * 16) ^ ((col & 7) << 6))] = v;
  }
  ((uint4*)ldsH[0])[tid] = make_uint4(0, 0, 0, 0);

  const int ctb = w * 2;
  // ---- z/r weight fragments -> PINNED registers (per-dword pin) ----
  uint4 wzu[2][8], wru[2][8];
#pragma unroll
  for (int ct = 0; ct < 2; ++ct) {
    int col = (ctb + ct) * 16 + fr;
#pragma unroll
    for (int ks = 0; ks < 8; ++ks) {
      uint4 a = *(const uint4*)&wht[(size_t)col * 256 + ks * 32 + fq * 8];
      uint4 b = *(const uint4*)&wht[(size_t)(256 + col) * 256 + ks * 32 + fq * 8];
      asm volatile("" : "+v"(a.x), "+v"(a.y), "+v"(a.z), "+v"(a.w));
      asm volatile("" : "+v"(b.x), "+v"(b.y), "+v"(b.z), "+v"(b.w));
      wzu[ct][ks] = a;
      wru[ct][ks] = b;
    }
  }
  f32 bhz0, bhz1, bhr0, bhr1, bhh0, bhh1;
  {
    int c0 = ctb * 16 + fr, c1 = (ctb + 1) * 16 + fr;
    bhz0 = bh[c0]; bhz1 = bh[c1];
    bhr0 = bh[256 + c0]; bhr1 = bh[256 + c1];
    bhh0 = bh[512 + c0]; bhh1 = bh[512 + c1];
  }
  f32 h00 = 0.f, h01 = 0.f, h02 = 0.f, h03 = 0.f;
  f32 h10 = 0.f, h11 = 0.f, h12 = 0.f, h13 = 0.f;

  // px packed offsets (ushort units): [t][hc][gate][row]
  const int off0 = ((ctb + 0) * 16 + fr) * 192 + fq * 4;
  const int off1 = ((ctb + 1) * 16 + fr) * 192 + fq * 4;
  const int rowbase = rg4 * 16;
  const int kb0 = ctb * 2 + (fr >> 3);
  const int kb1 = kb0 + 2;
  const int e2 = (fr & 7) * 2;

  uint2 pA0, pA1, pA2, pA3, pA4, pA5;
  uint2 pB0, pB1, pB2, pB3, pB4, pB5;
  PXLOAD(0, pA);
  __syncthreads();

#pragma unroll 1
  for (int t2 = 0; t2 < TT; t2 += 2) {
    STEP(t2, 0, pA, pB);
    STEP(t2 + 1, 1, pB, pA);
  }
  // tail: hseq[511] = h(512) in ldsH[0]
  {
    uint4 v = *(const uint4*)&ldsH[0][tid * 16];
    *(uint4*)&hseq[((size_t)511 * 64 + rowbase + (tid & 15)) * 256 + (tid >> 4) * 8] = v;
  }
}

// ---------------------------------------------------------------------------
// in-place row softmax over 512 bf16, one block per row
__global__ __launch_bounds__(256) void softmax_ip(ushort* __restrict__ p) {
  size_t row = blockIdx.x;
  uint* pr = (uint*)(p + row * 512);
  int tid = threadIdx.x;
  uint u = pr[tid];
  f32 v0 = bf2f((ushort)(u & 0xffff)), v1 = bf2f((ushort)(u >> 16));
  f32 m = fmaxf(v0, v1);
  for (int off = 32; off; off >>= 1) m = fmaxf(m, __shfl_xor(m, off));
  __shared__ f32 red[4];
  __shared__ f32 red2[4];
  if ((tid & 63) == 0) red[tid >> 6] = m;
  __syncthreads();
  m = fmaxf(fmaxf(red[0], red[1]), fmaxf(red[2], red[3]));
  f32 e0 = __expf(v0 - m), e1 = __expf(v1 - m);
  f32 s = e0 + e1;
  for (int off = 32; off; off >>= 1) s += __shfl_xor(s, off);
  if ((tid & 63) == 0) red2[tid >> 6] = s;
  __syncthreads();
  s = red2[0] + red2[1] + red2[2] + red2[3];
  f32 inv = 1.f / s;
  pr[tid] = (uint)f2bf(e0 * inv) | ((uint)f2bf(e1 * inv) << 16);
}

// ---------------------------------------------------------------------------
// CRF log-likelihood, one block (1 wave) per batch element.
__global__ __launch_bounds__(64) void crf_ll_k(
    const f32* __restrict__ logits, const int* __restrict__ y,
    const int* __restrict__ seq_len, const f32* __restrict__ trans,
    f32* __restrict__ out) {
  const int b = blockIdx.x, tid = threadIdx.x;
  __shared__ f32 tr[NN * NN];
  for (int i = tid; i < NN * NN; i += 64) tr[i] = trans[i];
  const f32* em = logits + (size_t)b * TT * NN;
  const int L = seq_len[b];
  const bool act = tid < NN;
  f32 Ecol[NN];
#pragma unroll
  for (int i = 0; i < NN; ++i)
    Ecol[i] = act ? __expf(trans[i * NN + tid]) : 0.f;
  f32 alpha = act ? em[tid] : -1e30f;
  __syncthreads();
  for (int t = 1; t < L; ++t) {
    f32 m = alpha;
    for (int off = 32; off; off >>= 1) m = fmaxf(m, __shfl_xor(m, off));
    f32 e = __expf(alpha - m);
    f32 s = 0.f;
#pragma unroll
    for (int i = 0; i < NN; ++i) s += __shfl(e, i) * Ecol[i];
    if (act) alpha = m + __logf(s) + em[t * NN + tid];
  }
  f32 us = 0.f, ts = 0.f;
  for (int t = tid; t < TT; t += 64) {
    if (t < L) {
      us += em[t * NN + y[b * TT + t]];
      if (t >= 1) ts += tr[y[b * TT + t - 1] * NN + y[b * TT + t]];
    }
  }
  for (int off = 32; off; off >>= 1) { us += __shfl_xor(us, off); ts += __shfl_xor(ts, off); }
  f32 m = alpha;
  for (int off = 32; off; off >>= 1) m = fmaxf(m, __shfl_xor(m, off));
  f32 e = __expf(alpha - m);
  f32 s = e;
  for (int off = 32; off; off >>= 1) s += __shfl_xor(s, off);
  if (tid == 0) out[(size_t)BB * TT + b] = us + ts - (m + __logf(s));
}

// CRF Viterbi decode, one block (1 wave) per batch element
__global__ __launch_bounds__(64) void crf_decode_k(
    const f32* __restrict__ logits, const int* __restrict__ seq_len,
    const f32* __restrict__ trans, f32* __restrict__ out) {
  const int b = blockIdx.x, tid = threadIdx.x;
  __shared__ f32 tr[NN][NN];
  __shared__ f32 al[2][NN];
  __shared__ unsigned char bp[TT - 1][NN];
  __shared__ unsigned char pr[TT];
  for (int i = tid; i < NN * NN; i += 64) tr[i / NN][i % NN] = trans[i];
  const f32* em = logits + (size_t)b * TT * NN;
  const int L = seq_len[b];
  if (tid < NN) al[0][tid] = em[tid];
  __syncthreads();
  int cur = 0;
  for (int t = 1; t < TT; ++t) {
    if (tid < NN) {
      if (t < L) {
        f32 m = -1e30f; int arg = 0;
        for (int i = 0; i < NN; ++i) {
          f32 v = al[cur][i] + tr[i][tid];
          if (v > m) { m = v; arg = i; }
        }
        al[cur ^ 1][tid] = m + em[t * NN + tid];
        bp[t - 1][tid] = (unsigned char)arg;
      } else {
        al[cur ^ 1][tid] = al[cur][tid];
        bp[t - 1][tid] = (unsigned char)tid;
      }
    }
    __syncthreads();
    cur ^= 1;
  }
  if (tid == 0) {
    f32 m = -1e30f; int last = 0;
    for (int i = 0; i < NN; ++i)
      if (al[cur][i] > m) { m = al[cur][i]; last = i; }
    int tag = last;
    for (int t = TT - 2; t >= 0; --t) { pr[t + 1] = (unsigned char)tag; tag = bp[t][tag]; }
    pr[0] = (unsigned char)tag;
  }
  __syncthreads();
  for (int t = tid; t < TT; t += 64)
    out[(size_t)b * TT + t] = (f32)pr[t];
}

// ---------------------------------------------------------------------------
extern "C" void kernel_launch(void* const* d_in, const int* in_sizes, int n_in,
                              void* d_out, int out_size, void* d_ws, size_t ws_size,
                              hipStream_t stream) {
  const int* x       = (const int*)d_in[0];
  const int* y       = (const int*)d_in[1];
  const int* seq_len = (const int*)d_in[2];
  const f32* embed   = (const f32*)d_in[3];
  const f32* wx_f    = (const f32*)d_in[4];
  const f32* wh_f    = (const f32*)d_in[5];
  const f32* b_f     = (const f32*)d_in[6];
  const f32* wx_b    = (const f32*)d_in[7];
  const f32* wh_b    = (const f32*)d_in[8];
  const f32* b_b     = (const f32*)d_in[9];
  const f32* wq      = (const f32*)d_in[10];
  const f32* bq      = (const f32*)d_in[11];
  const f32* wk      = (const f32*)d_in[12];
  const f32* bk      = (const f32*)d_in[13];
  const f32* wv      = (const f32*)d_in[14];
  const f32* bv      = (const f32*)d_in[15];
  const f32* wt      = (const f32*)d_in[16];
  const f32* bt      = (const f32*)d_in[17];
  const f32* trans   = (const f32*)d_in[18];
  f32* out = (f32*)d_out;

  char* ws = (char*)d_ws;
  ushort* ebf  = (ushort*)(ws + OFF_EBF);
  ushort* pxfb = (ushort*)(ws + OFF_PXF);
  ushort* pxbb = (ushort*)(ws + OFF_PXB);
  ushort* hfbf = (ushort*)(ws + OFF_HBF_F);
  ushort* hbbf = (ushort*)(ws + OFF_HBF_B);
  ushort* wxtf = (ushort*)(ws + OFF_WXTF);
  ushort* wxtb = (ushort*)(ws + OFF_WXTB);
  ushort* whtf = (ushort*)(ws + OFF_WHTF);
  ushort* whtb = (ushort*)(ws + OFF_WHTB);
  ushort* wqt  = (ushort*)(ws + OFF_WQT);
  ushort* wkt  = (ushort*)(ws + OFF_WKT);
  ushort* wvt  = (ushort*)(ws + OFF_WVT);
  ushort* wtt  = (ushort*)(ws + OFF_WTT);
  ushort* qbf = (ushort*)(ws + OFF_QBF);
  ushort* kbf = (ushort*)(ws + OFF_KBF);
  ushort* vbf = (ushort*)(ws + OFF_VBF);
  ushort* vT  = (ushort*)(ws + OFF_VT);
  ushort* scb = (ushort*)(ws + OFF_SCB);
  ushort* abf = (ushort*)(ws + OFF_ABF);
  f32*    lg  = (f32*)(ws + OFF_LG);

  // ---- setup converts ----
  conv_embed_k<<<8000, 256, 0, stream>>>(embed, ebf, 2048000);
  tconv_k<8><<<768, 256, 0, stream>>>(wx_f, wxtf, 196608, 768);
  tconv_k<8><<<768, 256, 0, stream>>>(wx_b, wxtb, 196608, 768);
  tconv_k<8><<<768, 256, 0, stream>>>(wh_f, whtf, 196608, 768);
  tconv_k<8><<<768, 256, 0, stream>>>(wh_b, whtb, 196608, 768);
  tconv_k<9><<<512, 256, 0, stream>>>(wq, wqt, 131072, 256);
  tconv_k<9><<<512, 256, 0, stream>>>(wk, wkt, 131072, 256);
  tconv_k<9><<<512, 256, 0, stream>>>(wv, wvt, 131072, 256);
  tconv_k<8><<<48, 256, 0, stream>>>(wt, wtt, 12288, 48);

  // ---- px (both dirs, packed layout), then pipelined MFMA scan ----
  mgemm<GM_PX><<<dim3(6, 256), 256, 0, stream>>>(
      ebf, nullptr, wxtf, nullptr, pxfb, b_f, x, 768, 256, 0);
  mgemm<GM_PX><<<dim3(6, 256), 256, 0, stream>>>(
      ebf, nullptr, wxtb, nullptr, pxbb, b_b, x, 768, 256, 1);
  gru_scan7<<<8, 512, 0, stream>>>(pxfb, pxbb, whtf, whtb, b_f, b_b, hfbf, hbbf);

  // ---- attention + logits, single pass over all 64 batches ----
  mgemm<GM_QKV><<<dim3(2, 256), 256, 0, stream>>>(
      hfbf, hbbf, wqt, nullptr, qbf, bq, nullptr, 256, 512, 0);
  mgemm<GM_QKV><<<dim3(2, 256), 256, 0, stream>>>(
      hfbf, hbbf, wkt, nullptr, kbf, bk, nullptr, 256, 512, 0);
  mgemm<GM_QKV><<<dim3(2, 256), 256, 0, stream>>>(
      hfbf, hbbf, wvt, nullptr, vbf, bv, nullptr, 256, 512, 0);
  tr_v_k<<<dim3(16, 8, 64), 256, 0, stream>>>(vbf, vT);
  mgemm<GM_SC><<<dim3(4, 4, 64), 256, 0, stream>>>(
      qbf, nullptr, kbf, nullptr, scb, nullptr, nullptr, 512, 256, 0);
  softmax_ip<<<BB * TT, 256, 0, stream>>>(scb);
  mgemm<GM_AV><<<dim3(2, 4, 64), 256, 0, stream>>>(
      scb, nullptr, vT, nullptr, abf, nullptr, nullptr, 256, 512, 0);
  mgemm<GM_LG><<<dim3(1, 256), 256, 0, stream>>>(
      abf, nullptr, wtt, lg, nullptr, bt, nullptr, 48, 256, 0);

  // ---- CRF ----
  crf_ll_k<<<BB, 64, 0, stream>>>(lg, y, seq_len, trans, out);
  crf_decode_k<<<BB, 64, 0, stream>>>(lg, seq_len, trans, out);
}

// Round 13
// 2755.268 us; speedup vs baseline: 1.2087x; 1.1422x over previous
//
#include <hip/hip_runtime.h>
#include <math.h>

typedef float f32;
typedef short short8 __attribute__((ext_vector_type(8)));
typedef float f32x4 __attribute__((ext_vector_type(4)));

#define TT 512
#define BB 64
#define DD 256
#define NN 48

// ===== workspace offsets (bytes). Peak ~153.0 MB =====
static const size_t OFF_EBF  = 0;                        // [32000][256] bf16
static const size_t OFF_PXF  = 16384000;                 // px packed [512][4][3][16][16][4][4] bf16
static const size_t OFF_PXB  = OFF_PXF + 50331648;
static const size_t OFF_HBF_F= OFF_PXB + 50331648;       // [512][64][256] bf16
static const size_t OFF_HBF_B= OFF_HBF_F + 16777216;
static const size_t OFF_WXTF = OFF_HBF_B + 16777216;     // [768][256] bf16
static const size_t OFF_WXTB = OFF_WXTF + 393216;
static const size_t OFF_WHTF = OFF_WXTB + 393216;        // [768][256] bf16 wh^T
static const size_t OFF_WHTB = OFF_WHTF + 393216;
static const size_t OFF_WQT  = OFF_WHTB + 393216;        // [256][512] bf16
static const size_t OFF_WKT  = OFF_WQT + 262144;
static const size_t OFF_WVT  = OFF_WKT + 262144;
static const size_t OFF_WTT  = OFF_WVT + 262144;         // [48][256] bf16
// attn phase aliases the (dead) px arena:
static const size_t OFF_QBF = OFF_PXF;                   // [64][512][256] bf16 (also ABF)
static const size_t OFF_KBF = OFF_QBF + 16777216;        // (also LG f32 after AV)
static const size_t OFF_VBF = OFF_KBF + 16777216;
static const size_t OFF_VT  = OFF_VBF + 16777216;        // [64][256][512] bf16
static const size_t OFF_SCB = OFF_VT  + 16777216;        // [64][512][512] bf16 (in-place SM)
static const size_t OFF_ABF = OFF_QBF;
static const size_t OFF_LG  = OFF_KBF;                   // [64][512][48] f32

__device__ __forceinline__ ushort f2bf(f32 f) {
  union { f32 f; unsigned u; } v; v.f = f;
  unsigned r = v.u + 0x7fffu + ((v.u >> 16) & 1u);   // RNE
  return (ushort)(r >> 16);
}
__device__ __forceinline__ f32 bf2f(ushort u) {
  union { unsigned u; f32 f; } v; v.u = ((unsigned)u) << 16; return v.f;
}
__device__ __forceinline__ f32 fsigmoid(f32 x) { return 1.f / (1.f + __expf(-x)); }
__device__ __forceinline__ f32 ftanh(f32 x) { return 1.f - 2.f / (__expf(2.f * x) + 1.f); }

// ---------------------------------------------------------------------------
template <int PL2>
__global__ __launch_bounds__(256) void tconv_k(
    const f32* __restrict__ in, ushort* __restrict__ out, int total, int Q) {
  int o = blockIdx.x * 256 + threadIdx.x;
  if (o >= total) return;
  int q = o >> PL2, p = o & ((1 << PL2) - 1);
  out[o] = f2bf(in[(size_t)p * Q + q]);
}

__global__ __launch_bounds__(256) void conv_embed_k(
    const f32* __restrict__ in, ushort* __restrict__ out, int n4) {
  int i = blockIdx.x * 256 + threadIdx.x;
  if (i >= n4) return;
  float4 v = ((const float4*)in)[i];
  ushort4 o;
  o.x = f2bf(v.x); o.y = f2bf(v.y); o.z = f2bf(v.z); o.w = f2bf(v.w);
  ((ushort4*)out)[i] = o;
}

__global__ __launch_bounds__(256) void tr_v_k(
    const ushort* __restrict__ in, ushort* __restrict__ out) {
  __shared__ ushort tile[32][33];
  int b = blockIdx.z;
  int s0 = blockIdx.x * 32, d0 = blockIdx.y * 32;
  int xc = threadIdx.x & 31, y0 = threadIdx.x >> 5;
  for (int yy = y0; yy < 32; yy += 8)
    tile[yy][xc] = in[((size_t)b * 512 + s0 + yy) * 256 + d0 + xc];
  __syncthreads();
  for (int yy = y0; yy < 32; yy += 8)
    out[((size_t)b * 256 + d0 + yy) * 512 + s0 + xc] = tile[xc][yy];
}

// ---------------------------------------------------------------------------
enum { GM_PX = 0, GM_QKV = 1, GM_SC = 2, GM_AV = 3, GM_LG = 4 };

template <int MODE>
__global__ __launch_bounds__(256) void mgemm(
    const ushort* __restrict__ Aa, const ushort* __restrict__ Ab,
    const ushort* __restrict__ Bt,
    f32* __restrict__ Cf, ushort* __restrict__ Cb,
    const f32* __restrict__ bias, const int* __restrict__ xi,
    int Ndim, int K, int rev) {
  const int m0 = blockIdx.y * 128;
  const int n0 = blockIdx.x * 128;
  const int bz = blockIdx.z;
  const int tid = threadIdx.x;
  const int l = tid & 63, w = tid >> 6;
  const int wr = w >> 1, wc = w & 1;
  __shared__ __align__(16) short Al[128 * 40];
  __shared__ __align__(16) short Bl[128 * 40];
  f32x4 acc[4][4] = {};

  const int rowa = tid >> 1;
  const int kha = (tid & 1) * 16;
  const int rA = m0 + rowa;
  const ushort* aBase = nullptr;
  const ushort* aBase2 = nullptr;
  if constexpr (MODE == GM_PX) {
    int tg = rA >> 6, b = rA & 63;
    int ts = rev ? (511 - tg) : tg;
    aBase = Aa + (size_t)xi[b * 512 + ts] * 256;
  } else if constexpr (MODE == GM_QKV) {
    int bl = rA >> 9, t = rA & 511;
    aBase = Aa + ((size_t)(t * 64 + bl)) * 256;
    aBase2 = Ab + ((size_t)((511 - t) * 64 + bl)) * 256;
  } else if constexpr (MODE == GM_SC) {
    aBase = Aa + ((size_t)(bz * 512 + rA)) * 256;
  } else if constexpr (MODE == GM_AV) {
    aBase = Aa + ((size_t)(bz * 512 + rA)) * 512;
  } else {
    aBase = Aa + (size_t)rA * 256;
  }
  const int rowb = tid >> 1;
  const int khb = (tid & 1) * 16;
  int rowg = n0 + rowb;
  if constexpr (MODE == GM_SC) rowg += bz * 512;
  if constexpr (MODE == GM_AV) rowg += bz * 256;
  const ushort* bBase = Bt + (size_t)rowg * K;
  const bool bValid = (MODE != GM_LG) || (n0 + rowb < Ndim);

  for (int k0 = 0; k0 < K; k0 += 32) {
    {
      int kk = k0 + kha;
      const ushort* src;
      if constexpr (MODE == GM_QKV)
        src = (kk < 256) ? aBase + kk : aBase2 + (kk - 256);
      else
        src = aBase + kk;
      uint4 a0 = *(const uint4*)src;
      uint4 a1 = *(const uint4*)(src + 8);
      *(uint4*)&Al[rowa * 40 + kha] = a0;
      *(uint4*)&Al[rowa * 40 + kha + 8] = a1;
    }
    {
      uint4 v0 = make_uint4(0, 0, 0, 0), v1 = make_uint4(0, 0, 0, 0);
      if (bValid) {
        const ushort* src = bBase + k0 + khb;
        v0 = *(const uint4*)src;
        v1 = *(const uint4*)(src + 8);
      }
      *(uint4*)&Bl[rowb * 40 + khb] = v0;
      *(uint4*)&Bl[rowb * 40 + khb + 8] = v1;
    }
    __syncthreads();
    const int fr = l & 15, fg = l >> 4;
    short8 af[4], bfr[4];
#pragma unroll
    for (int mf = 0; mf < 4; ++mf)
      af[mf] = *(const short8*)&Al[(wr * 64 + mf * 16 + fr) * 40 + fg * 8];
#pragma unroll
    for (int nf = 0; nf < 4; ++nf)
      bfr[nf] = *(const short8*)&Bl[(wc * 64 + nf * 16 + fr) * 40 + fg * 8];
#pragma unroll
    for (int mf = 0; mf < 4; ++mf)
#pragma unroll
      for (int nf = 0; nf < 4; ++nf)
        acc[mf][nf] = __builtin_amdgcn_mfma_f32_16x16x32_bf16(
            af[mf], bfr[nf], acc[mf][nf], 0, 0, 0);
    __syncthreads();
  }

  const int fr = l & 15, fq = l >> 4;
#pragma unroll
  for (int mf = 0; mf < 4; ++mf) {
#pragma unroll
    for (int nf = 0; nf < 4; ++nf) {
      int col = n0 + wc * 64 + nf * 16 + fr;
      f32 bs = 0.f;
      if (bias && col < Ndim) bs = bias[col];
#pragma unroll
      for (int rg = 0; rg < 4; ++rg) {
        int row = m0 + wr * 64 + mf * 16 + fq * 4 + rg;
        f32 vv = acc[mf][nf][rg] + bs;
        if constexpr (MODE == GM_PX) {
          // packed px: [t][rg4][gate][ct][fr][fq][ri]
          int tg = row >> 6, b = row & 63;
          int gate = col >> 8, hc = col & 255;
          int rg4b = b >> 4, lr = b & 15;
          size_t idx = (size_t)tg * 49152 + (size_t)rg4b * 12288 +
                       (size_t)gate * 4096 + (size_t)(hc >> 4) * 256 +
                       (hc & 15) * 16 + (lr >> 2) * 4 + (lr & 3);
          Cb[idx] = f2bf(vv);
        } else if constexpr (MODE == GM_QKV)
          Cb[(size_t)row * 256 + col] = f2bf(vv);
        else if constexpr (MODE == GM_SC)
          Cb[((size_t)bz * 512 + row) * 512 + col] = f2bf(vv);
        else if constexpr (MODE == GM_AV)
          Cb[((size_t)bz * 512 + row) * 256 + col] = f2bf(vv);
        else {
          if (col < Ndim) Cf[(size_t)row * 48 + col] = vv;
        }
      }
    }
  }
}

// ---------------------------------------------------------------------------
// GRU scan v8: 8 WGs = 2 dir x 4 row-groups (16 rows), 1024 thr (16 waves).
// Wave w owns 16 h-cols: z/r weights = 64 VGPRs/wave (fits 128-reg cap of
// launch_bounds(1024,4) -> allocator keeps them resident). Wh in swizzled
// LDS; h double-buffered k-block-major; coalesced packed px (3 uint2/thr).
#define MFMA_B16 __builtin_amdgcn_mfma_f32_16x16x32_bf16

#define PXLOAD(T, P) {                                         \
  size_t tb_ = (size_t)(T) * 49152;                            \
  P##0 = *(const uint2*)(px + tb_ + offp);                     \
  P##1 = *(const uint2*)(px + tb_ + offp + 4096);              \
  P##2 = *(const uint2*)(px + tb_ + offp + 8192);              \
}

#define GATE1(RI, UZ, UR, UH)                                  \
{                                                              \
  f32 zv_ = fsigmoid(az[RI] + bhz + bf2f((ushort)(UZ)));       \
  f32 rv_ = fsigmoid(ar[RI] + bhr + bf2f((ushort)(UR)));       \
  f32 hc_ = ftanh(bf2f((ushort)(UH)) + rv_ * (ah[RI] + bhh));  \
  f32 hn_ = zv_ * h0##RI + (1.f - zv_) * hc_;                  \
  h0##RI = hn_;                                                \
  *(ushort*)&dst_[(kb0 * 16 + fq * 4 + (RI)) * 16 + e2] = f2bf(hn_); \
}

#define STEP(T, BUF, PC, PN) {                                 \
  if ((T) + 1 < TT) PXLOAD((T) + 1, PN);                       \
  if ((T) > 0) {                                               \
    uint2 v_ = *(const uint2*)&ldsH[BUF][(ckb * 16 + crow) * 16 + chalf * 8]; \
    *(uint2*)&hseq[(((size_t)(T) - 1) * 64 + rowbase + crow) * 256 + ckb * 8 + chalf * 4] = v_; \
  }                                                            \
  uint2 q0_ = PC##0, q1_ = PC##1, q2_ = PC##2;                 \
  f32x4 az = {}, ar = {}, ah = {};                             \
  _Pragma("unroll")                                            \
  for (int ks = 0; ks < 8; ++ks) {                             \
    short8 a_  = *(const short8*)&ldsH[BUF][((ks * 4 + fq) * 16 + fr) * 16]; \
    short8 wh8 = *(const short8*)&ldsWh[wcol * 512 + ((ks * 64 + fq * 16) ^ ((wcol & 7) << 6))]; \
    az = MFMA_B16(a_, wz[ks], az, 0, 0, 0);                    \
    ar = MFMA_B16(a_, wrg[ks], ar, 0, 0, 0);                   \
    ah = MFMA_B16(a_, wh8, ah, 0, 0, 0);                       \
  }                                                            \
  char* dst_ = ldsH[(BUF) ^ 1];                                \
  GATE1(0, q0_.x,       q1_.x,       q2_.x)                    \
  GATE1(1, q0_.x >> 16, q1_.x >> 16, q2_.x >> 16)              \
  GATE1(2, q0_.y,       q1_.y,       q2_.y)                    \
  GATE1(3, q0_.y >> 16, q1_.y >> 16, q2_.y >> 16)              \
  __syncthreads();                                             \
}

__global__ __launch_bounds__(1024, 4) void gru_scan8(
    const ushort* __restrict__ pxf, const ushort* __restrict__ pxb,
    const ushort* __restrict__ whtf, const ushort* __restrict__ whtb,
    const f32* __restrict__ b_f, const f32* __restrict__ b_b,
    ushort* __restrict__ hfbf, ushort* __restrict__ hbbf) {
  const int dir = blockIdx.x >> 2;
  const int rg4 = blockIdx.x & 3;
  const int tid = threadIdx.x;
  const int w = tid >> 6, l = tid & 63;       // wave = ct index (0..15)
  const int fr = l & 15, fq = l >> 4;
  const ushort* pxd = dir ? pxb : pxf;
  const ushort* wht = dir ? whtb : whtf;
  const f32* bh = (dir ? b_b : b_f) + 768;
  ushort* hseq = dir ? hbbf : hfbf;

  __shared__ __align__(16) char ldsWh[131072];  // [col 0..255][512B] swz (col&7)<<6
  __shared__ __align__(16) char ldsH[2][8192];  // [kblk 0..31][row 0..15][16B]

  // stage Wh (gate rows 512..767)
#pragma unroll
  for (int i = 0; i < 8; ++i) {
    int idx = i * 1024 + tid;
    int col = idx >> 5, kc = idx & 31;
    uint4 v = *(const uint4*)&wht[(size_t)(512 + col) * 256 + kc * 8];
    *(uint4*)&ldsWh[col * 512 + ((kc * 16) ^ ((col & 7) << 6))] = v;
  }
  if (tid < 512) ((uint4*)ldsH[0])[tid] = make_uint4(0, 0, 0, 0);

  const int wcol = w * 16 + fr;               // this thread's h-column
  // z/r weight fragments -> registers (64 VGPRs)
  short8 wz[8], wrg[8];
#pragma unroll
  for (int ks = 0; ks < 8; ++ks) {
    wz[ks]  = *(const short8*)&wht[(size_t)wcol * 256 + ks * 32 + fq * 8];
    wrg[ks] = *(const short8*)&wht[(size_t)(256 + wcol) * 256 + ks * 32 + fq * 8];
  }
  const f32 bhz = bh[wcol], bhr = bh[256 + wcol], bhh = bh[512 + wcol];
  f32 h00 = 0.f, h01 = 0.f, h02 = 0.f, h03 = 0.f;

  // packed px offset (ushort units): [t][rg4][gate][ct=w][fr][fq][ri]
  const ushort* px = pxd + (size_t)rg4 * 12288;
  const int offp = w * 256 + fr * 16 + fq * 4;
  const int rowbase = rg4 * 16;
  const int kb0 = wcol >> 3;                  // h write: col/8
  const int e2 = (wcol & 7) * 2;
  // cooperative hseq store assignment
  const int ckb = (tid >> 1) >> 4;            // 0..31
  const int crow = (tid >> 1) & 15;           // 0..15
  const int chalf = tid & 1;

  uint2 pA0, pA1, pA2;
  uint2 pB0, pB1, pB2;
  PXLOAD(0, pA);
  __syncthreads();

#pragma unroll 1
  for (int t2 = 0; t2 < TT; t2 += 2) {
    STEP(t2, 0, pA, pB);
    STEP(t2 + 1, 1, pB, pA);
  }
  // tail: hseq[511] = h(512) in ldsH[0]
  {
    uint2 v = *(const uint2*)&ldsH[0][(ckb * 16 + crow) * 16 + chalf * 8];
    *(uint2*)&hseq[((size_t)511 * 64 + rowbase + crow) * 256 + ckb * 8 + chalf * 4] = v;
  }
}

// ---------------------------------------------------------------------------
__global__ __launch_bounds__(256) void softmax_ip(ushort* __restrict__ p) {
  size_t row = blockIdx.x;
  uint* pr = (uint*)(p + row * 512);
  int tid = threadIdx.x;
  uint u = pr[tid];
  f32 v0 = bf2f((ushort)(u & 0xffff)), v1 = bf2f((ushort)(u >> 16));
  f32 m = fmaxf(v0, v1);
  for (int off = 32; off; off >>= 1) m = fmaxf(m, __shfl_xor(m, off));
  __shared__ f32 red[4];
  __shared__ f32 red2[4];
  if ((tid & 63) == 0) red[tid >> 6] = m;
  __syncthreads();
  m = fmaxf(fmaxf(red[0], red[1]), fmaxf(red[2], red[3]));
  f32 e0 = __expf(v0 - m), e1 = __expf(v1 - m);
  f32 s = e0 + e1;
  for (int off = 32; off; off >>= 1) s += __shfl_xor(s, off);
  if ((tid & 63) == 0) red2[tid >> 6] = s;
  __syncthreads();
  s = red2[0] + red2[1] + red2[2] + red2[3];
  f32 inv = 1.f / s;
  pr[tid] = (uint)f2bf(e0 * inv) | ((uint)f2bf(e1 * inv) << 16);
}

// ---------------------------------------------------------------------------
__global__ __launch_bounds__(64) void crf_ll_k(
    const f32* __restrict__ logits, const int* __restrict__ y,
    const int* __restrict__ seq_len, const f32* __restrict__ trans,
    f32* __restrict__ out) {
  const int b = blockIdx.x, tid = threadIdx.x;
  __shared__ f32 tr[NN * NN];
  for (int i = tid; i < NN * NN; i += 64) tr[i] = trans[i];
  const f32* em = logits + (size_t)b * TT * NN;
  const int L = seq_len[b];
  const bool act = tid < NN;
  f32 Ecol[NN];
#pragma unroll
  for (int i = 0; i < NN; ++i)
    Ecol[i] = act ? __expf(trans[i * NN + tid]) : 0.f;
  f32 alpha = act ? em[tid] : -1e30f;
  __syncthreads();
  for (int t = 1; t < L; ++t) {
    f32 m = alpha;
    for (int off = 32; off; off >>= 1) m = fmaxf(m, __shfl_xor(m, off));
    f32 e = __expf(alpha - m);
    f32 s = 0.f;
#pragma unroll
    for (int i = 0; i < NN; ++i) s += __shfl(e, i) * Ecol[i];
    if (act) alpha = m + __logf(s) + em[t * NN + tid];
  }
  f32 us = 0.f, ts = 0.f;
  for (int t = tid; t < TT; t += 64) {
    if (t < L) {
      us += em[t * NN + y[b * TT + t]];
      if (t >= 1) ts += tr[y[b * TT + t - 1] * NN + y[b * TT + t]];
    }
  }
  for (int off = 32; off; off >>= 1) { us += __shfl_xor(us, off); ts += __shfl_xor(ts, off); }
  f32 m = alpha;
  for (int off = 32; off; off >>= 1) m = fmaxf(m, __shfl_xor(m, off));
  f32 e = __expf(alpha - m);
  f32 s = e;
  for (int off = 32; off; off >>= 1) s += __shfl_xor(s, off);
  if (tid == 0) out[(size_t)BB * TT + b] = us + ts - (m + __logf(s));
}

__global__ __launch_bounds__(64) void crf_decode_k(
    const f32* __restrict__ logits, const int* __restrict__ seq_len,
    const f32* __restrict__ trans, f32* __restrict__ out) {
  const int b = blockIdx.x, tid = threadIdx.x;
  __shared__ f32 tr[NN][NN];
  __shared__ f32 al[2][NN];
  __shared__ unsigned char bp[TT - 1][NN];
  __shared__ unsigned char pr[TT];
  for (int i = tid; i < NN * NN; i += 64) tr[i / NN][i % NN] = trans[i];
  const f32* em = logits + (size_t)b * TT * NN;
  const int L = seq_len[b];
  if (tid < NN) al[0][tid] = em[tid];
  __syncthreads();
  int cur = 0;
  for (int t = 1; t < TT; ++t) {
    if (tid < NN) {
      if (t < L) {
        f32 m = -1e30f; int arg = 0;
        for (int i = 0; i < NN; ++i) {
          f32 v = al[cur][i] + tr[i][tid];
          if (v > m) { m = v; arg = i; }
        }
        al[cur ^ 1][tid] = m + em[t * NN + tid];
        bp[t - 1][tid] = (unsigned char)arg;
      } else {
        al[cur ^ 1][tid] = al[cur][tid];
        bp[t - 1][tid] = (unsigned char)tid;
      }
    }
    __syncthreads();
    cur ^= 1;
  }
  if (tid == 0) {
    f32 m = -1e30f; int last = 0;
    for (int i = 0; i < NN; ++i)
      if (al[cur][i] > m) { m = al[cur][i]; last = i; }
    int tag = last;
    for (int t = TT - 2; t >= 0; --t) { pr[t + 1] = (unsigned char)tag; tag = bp[t][tag]; }
    pr[0] = (unsigned char)tag;
  }
  __syncthreads();
  for (int t = tid; t < TT; t += 64)
    out[(size_t)b * TT + t] = (f32)pr[t];
}

// ---------------------------------------------------------------------------
extern "C" void kernel_launch(void* const* d_in, const int* in_sizes, int n_in,
                              void* d_out, int out_size, void* d_ws, size_t ws_size,
                              hipStream_t stream) {
  const int* x       = (const int*)d_in[0];
  const int* y       = (const int*)d_in[1];
  const int* seq_len = (const int*)d_in[2];
  const f32* embed   = (const f32*)d_in[3];
  const f32* wx_f    = (const f32*)d_in[4];
  const f32* wh_f    = (const f32*)d_in[5];
  const f32* b_f     = (const f32*)d_in[6];
  const f32* wx_b    = (const f32*)d_in[7];
  const f32* wh_b    = (const f32*)d_in[8];
  const f32* b_b     = (const f32*)d_in[9];
  const f32* wq      = (const f32*)d_in[10];
  const f32* bq      = (const f32*)d_in[11];
  const f32* wk      = (const f32*)d_in[12];
  const f32* bk      = (const f32*)d_in[13];
  const f32* wv      = (const f32*)d_in[14];
  const f32* bv      = (const f32*)d_in[15];
  const f32* wt      = (const f32*)d_in[16];
  const f32* bt      = (const f32*)d_in[17];
  const f32* trans   = (const f32*)d_in[18];
  f32* out = (f32*)d_out;

  char* ws = (char*)d_ws;
  ushort* ebf  = (ushort*)(ws + OFF_EBF);
  ushort* pxfb = (ushort*)(ws + OFF_PXF);
  ushort* pxbb = (ushort*)(ws + OFF_PXB);
  ushort* hfbf = (ushort*)(ws + OFF_HBF_F);
  ushort* hbbf = (ushort*)(ws + OFF_HBF_B);
  ushort* wxtf = (ushort*)(ws + OFF_WXTF);
  ushort* wxtb = (ushort*)(ws + OFF_WXTB);
  ushort* whtf = (ushort*)(ws + OFF_WHTF);
  ushort* whtb = (ushort*)(ws + OFF_WHTB);
  ushort* wqt  = (ushort*)(ws + OFF_WQT);
  ushort* wkt  = (ushort*)(ws + OFF_WKT);
  ushort* wvt  = (ushort*)(ws + OFF_WVT);
  ushort* wtt  = (ushort*)(ws + OFF_WTT);
  ushort* qbf = (ushort*)(ws + OFF_QBF);
  ushort* kbf = (ushort*)(ws + OFF_KBF);
  ushort* vbf = (ushort*)(ws + OFF_VBF);
  ushort* vT  = (ushort*)(ws + OFF_VT);
  ushort* scb = (ushort*)(ws + OFF_SCB);
  ushort* abf = (ushort*)(ws + OFF_ABF);
  f32*    lg  = (f32*)(ws + OFF_LG);

  // ---- setup converts ----
  conv_embed_k<<<8000, 256, 0, stream>>>(embed, ebf, 2048000);
  tconv_k<8><<<768, 256, 0, stream>>>(wx_f, wxtf, 196608, 768);
  tconv_k<8><<<768, 256, 0, stream>>>(wx_b, wxtb, 196608, 768);
  tconv_k<8><<<768, 256, 0, stream>>>(wh_f, whtf, 196608, 768);
  tconv_k<8><<<768, 256, 0, stream>>>(wh_b, whtb, 196608, 768);
  tconv_k<9><<<512, 256, 0, stream>>>(wq, wqt, 131072, 256);
  tconv_k<9><<<512, 256, 0, stream>>>(wk, wkt, 131072, 256);
  tconv_k<9><<<512, 256, 0, stream>>>(wv, wvt, 131072, 256);
  tconv_k<8><<<48, 256, 0, stream>>>(wt, wtt, 12288, 48);

  // ---- px (both dirs, packed layout), then 16-wave MFMA scan ----
  mgemm<GM_PX><<<dim3(6, 256), 256, 0, stream>>>(
      ebf, nullptr, wxtf, nullptr, pxfb, b_f, x, 768, 256, 0);
  mgemm<GM_PX><<<dim3(6, 256), 256, 0, stream>>>(
      ebf, nullptr, wxtb, nullptr, pxbb, b_b, x, 768, 256, 1);
  gru_scan8<<<8, 1024, 0, stream>>>(pxfb, pxbb, whtf, whtb, b_f, b_b, hfbf, hbbf);

  // ---- attention + logits, single pass over all 64 batches ----
  mgemm<GM_QKV><<<dim3(2, 256), 256, 0, stream>>>(
      hfbf, hbbf, wqt, nullptr, qbf, bq, nullptr, 256, 512, 0);
  mgemm<GM_QKV><<<dim3(2, 256), 256, 0, stream>>>(
      hfbf, hbbf, wkt, nullptr, kbf, bk, nullptr, 256, 512, 0);
  mgemm<GM_QKV><<<dim3(2, 256), 256, 0, stream>>>(
      hfbf, hbbf, wvt, nullptr, vbf, bv, nullptr, 256, 512, 0);
  tr_v_k<<<dim3(16, 8, 64), 256, 0, stream>>>(vbf, vT);
  mgemm<GM_SC><<<dim3(4, 4, 64), 256, 0, stream>>>(
      qbf, nullptr, kbf, nullptr, scb, nullptr, nullptr, 512, 256, 0);
  softmax_ip<<<BB * TT, 256, 0, stream>>>(scb);
  mgemm<GM_AV><<<dim3(2, 4, 64), 256, 0, stream>>>(
      scb, nullptr, vT, nullptr, abf, nullptr, nullptr, 256, 512, 0);
  mgemm<GM_LG><<<dim3(1, 256), 256, 0, stream>>>(
      abf, nullptr, wtt, lg, nullptr, bt, nullptr, 48, 256, 0);

  // ---- CRF ----
  crf_ll_k<<<BB, 64, 0, stream>>>(lg, y, seq_len, trans, out);
  crf_decode_k<<<BB, 64, 0, stream>>>(lg, seq_len, trans, out);
}

// Round 14
// 2732.027 us; speedup vs baseline: 1.2190x; 1.0085x over previous
//
#include <hip/hip_runtime.h>
#include <math.h>

typedef float f32;
typedef short short8 __attribute__((ext_vector_type(8)));
typedef float f32x4 __attribute__((ext_vector_type(4)));

#define TT 512
#define BB 64
#define DD 256
#define NN 48

// ===== workspace offsets (bytes). Peak ~153.0 MB =====
static const size_t OFF_EBF  = 0;                        // [32000][256] bf16
static const size_t OFF_PXF  = 16384000;                 // px packed [512][4][3][8][16][4][2][4] bf16
static const size_t OFF_PXB  = OFF_PXF + 50331648;
static const size_t OFF_HBF_F= OFF_PXB + 50331648;       // [512][64][256] bf16
static const size_t OFF_HBF_B= OFF_HBF_F + 16777216;
static const size_t OFF_WXTF = OFF_HBF_B + 16777216;     // [768][256] bf16
static const size_t OFF_WXTB = OFF_WXTF + 393216;
static const size_t OFF_WHTF = OFF_WXTB + 393216;        // [768][256] bf16 wh^T
static const size_t OFF_WHTB = OFF_WHTF + 393216;
static const size_t OFF_WQT  = OFF_WHTB + 393216;        // [256][512] bf16
static const size_t OFF_WKT  = OFF_WQT + 262144;
static const size_t OFF_WVT  = OFF_WKT + 262144;
static const size_t OFF_WTT  = OFF_WVT + 262144;         // [48][256] bf16
// attn phase aliases the (dead) px arena:
static const size_t OFF_QBF = OFF_PXF;                   // [64][512][256] bf16 (also ABF)
static const size_t OFF_KBF = OFF_QBF + 16777216;        // (also LG f32 after AV)
static const size_t OFF_VBF = OFF_KBF + 16777216;
static const size_t OFF_VT  = OFF_VBF + 16777216;        // [64][256][512] bf16
static const size_t OFF_SCB = OFF_VT  + 16777216;        // [64][512][512] bf16 (in-place SM)
static const size_t OFF_ABF = OFF_QBF;
static const size_t OFF_LG  = OFF_KBF;                   // [64][512][48] f32

__device__ __forceinline__ ushort f2bf(f32 f) {
  union { f32 f; unsigned u; } v; v.f = f;
  unsigned r = v.u + 0x7fffu + ((v.u >> 16) & 1u);   // RNE
  return (ushort)(r >> 16);
}
__device__ __forceinline__ f32 bf2f(ushort u) {
  union { unsigned u; f32 f; } v; v.u = ((unsigned)u) << 16; return v.f;
}
__device__ __forceinline__ f32 fsigmoid(f32 x) { return 1.f / (1.f + __expf(-x)); }
__device__ __forceinline__ f32 ftanh(f32 x) { return 1.f - 2.f / (__expf(2.f * x) + 1.f); }

// ---------------------------------------------------------------------------
template <int PL2>
__global__ __launch_bounds__(256) void tconv_k(
    const f32* __restrict__ in, ushort* __restrict__ out, int total, int Q) {
  int o = blockIdx.x * 256 + threadIdx.x;
  if (o >= total) return;
  int q = o >> PL2, p = o & ((1 << PL2) - 1);
  out[o] = f2bf(in[(size_t)p * Q + q]);
}

__global__ __launch_bounds__(256) void conv_embed_k(
    const f32* __restrict__ in, ushort* __restrict__ out, int n4) {
  int i = blockIdx.x * 256 + threadIdx.x;
  if (i >= n4) return;
  float4 v = ((const float4*)in)[i];
  ushort4 o;
  o.x = f2bf(v.x); o.y = f2bf(v.y); o.z = f2bf(v.z); o.w = f2bf(v.w);
  ((ushort4*)out)[i] = o;
}

__global__ __launch_bounds__(256) void tr_v_k(
    const ushort* __restrict__ in, ushort* __restrict__ out) {
  __shared__ ushort tile[32][33];
  int b = blockIdx.z;
  int s0 = blockIdx.x * 32, d0 = blockIdx.y * 32;
  int xc = threadIdx.x & 31, y0 = threadIdx.x >> 5;
  for (int yy = y0; yy < 32; yy += 8)
    tile[yy][xc] = in[((size_t)b * 512 + s0 + yy) * 256 + d0 + xc];
  __syncthreads();
  for (int yy = y0; yy < 32; yy += 8)
    out[((size_t)b * 256 + d0 + yy) * 512 + s0 + xc] = tile[xc][yy];
}

// ---------------------------------------------------------------------------
enum { GM_PX = 0, GM_QKV = 1, GM_SC = 2, GM_AV = 3, GM_LG = 4 };

template <int MODE>
__global__ __launch_bounds__(256) void mgemm(
    const ushort* __restrict__ Aa, const ushort* __restrict__ Ab,
    const ushort* __restrict__ Bt,
    f32* __restrict__ Cf, ushort* __restrict__ Cb,
    const f32* __restrict__ bias, const int* __restrict__ xi,
    int Ndim, int K, int rev) {
  const int m0 = blockIdx.y * 128;
  const int n0 = blockIdx.x * 128;
  const int bz = blockIdx.z;
  const int tid = threadIdx.x;
  const int l = tid & 63, w = tid >> 6;
  const int wr = w >> 1, wc = w & 1;
  __shared__ __align__(16) short Al[128 * 40];
  __shared__ __align__(16) short Bl[128 * 40];
  f32x4 acc[4][4] = {};

  const int rowa = tid >> 1;
  const int kha = (tid & 1) * 16;
  const int rA = m0 + rowa;
  const ushort* aBase = nullptr;
  const ushort* aBase2 = nullptr;
  if constexpr (MODE == GM_PX) {
    int tg = rA >> 6, b = rA & 63;
    int ts = rev ? (511 - tg) : tg;
    aBase = Aa + (size_t)xi[b * 512 + ts] * 256;
  } else if constexpr (MODE == GM_QKV) {
    int bl = rA >> 9, t = rA & 511;
    aBase = Aa + ((size_t)(t * 64 + bl)) * 256;
    aBase2 = Ab + ((size_t)((511 - t) * 64 + bl)) * 256;
  } else if constexpr (MODE == GM_SC) {
    aBase = Aa + ((size_t)(bz * 512 + rA)) * 256;
  } else if constexpr (MODE == GM_AV) {
    aBase = Aa + ((size_t)(bz * 512 + rA)) * 512;
  } else {
    aBase = Aa + (size_t)rA * 256;
  }
  const int rowb = tid >> 1;
  const int khb = (tid & 1) * 16;
  int rowg = n0 + rowb;
  if constexpr (MODE == GM_SC) rowg += bz * 512;
  if constexpr (MODE == GM_AV) rowg += bz * 256;
  const ushort* bBase = Bt + (size_t)rowg * K;
  const bool bValid = (MODE != GM_LG) || (n0 + rowb < Ndim);

  for (int k0 = 0; k0 < K; k0 += 32) {
    {
      int kk = k0 + kha;
      const ushort* src;
      if constexpr (MODE == GM_QKV)
        src = (kk < 256) ? aBase + kk : aBase2 + (kk - 256);
      else
        src = aBase + kk;
      uint4 a0 = *(const uint4*)src;
      uint4 a1 = *(const uint4*)(src + 8);
      *(uint4*)&Al[rowa * 40 + kha] = a0;
      *(uint4*)&Al[rowa * 40 + kha + 8] = a1;
    }
    {
      uint4 v0 = make_uint4(0, 0, 0, 0), v1 = make_uint4(0, 0, 0, 0);
      if (bValid) {
        const ushort* src = bBase + k0 + khb;
        v0 = *(const uint4*)src;
        v1 = *(const uint4*)(src + 8);
      }
      *(uint4*)&Bl[rowb * 40 + khb] = v0;
      *(uint4*)&Bl[rowb * 40 + khb + 8] = v1;
    }
    __syncthreads();
    const int fr = l & 15, fg = l >> 4;
    short8 af[4], bfr[4];
#pragma unroll
    for (int mf = 0; mf < 4; ++mf)
      af[mf] = *(const short8*)&Al[(wr * 64 + mf * 16 + fr) * 40 + fg * 8];
#pragma unroll
    for (int nf = 0; nf < 4; ++nf)
      bfr[nf] = *(const short8*)&Bl[(wc * 64 + nf * 16 + fr) * 40 + fg * 8];
#pragma unroll
    for (int mf = 0; mf < 4; ++mf)
#pragma unroll
      for (int nf = 0; nf < 4; ++nf)
        acc[mf][nf] = __builtin_amdgcn_mfma_f32_16x16x32_bf16(
            af[mf], bfr[nf], acc[mf][nf], 0, 0, 0);
    __syncthreads();
  }

  const int fr = l & 15, fq = l >> 4;
#pragma unroll
  for (int mf = 0; mf < 4; ++mf) {
#pragma unroll
    for (int nf = 0; nf < 4; ++nf) {
      int col = n0 + wc * 64 + nf * 16 + fr;
      f32 bs = 0.f;
      if (bias && col < Ndim) bs = bias[col];
#pragma unroll
      for (int rg = 0; rg < 4; ++rg) {
        int row = m0 + wr * 64 + mf * 16 + fq * 4 + rg;
        f32 vv = acc[mf][nf][rg] + bs;
        if constexpr (MODE == GM_PX) {
          // packed px: [t][rg4][gate][w][fr][fq][ct][ri]
          int tg = row >> 6, b = row & 63;
          int gate = col >> 8, hc = col & 255;
          int wv2 = hc >> 5, ctb2 = (hc >> 4) & 1, frb = hc & 15;
          int rg4b = b >> 4, lr = b & 15;
          size_t idx = (size_t)tg * 49152 + (size_t)rg4b * 12288 +
                       (size_t)gate * 4096 + (size_t)wv2 * 512 +
                       frb * 32 + (lr >> 2) * 8 + ctb2 * 4 + (lr & 3);
          Cb[idx] = f2bf(vv);
        } else if constexpr (MODE == GM_QKV)
          Cb[(size_t)row * 256 + col] = f2bf(vv);
        else if constexpr (MODE == GM_SC)
          Cb[((size_t)bz * 512 + row) * 512 + col] = f2bf(vv);
        else if constexpr (MODE == GM_AV)
          Cb[((size_t)bz * 512 + row) * 256 + col] = f2bf(vv);
        else {
          if (col < Ndim) Cf[(size_t)row * 48 + col] = vv;
        }
      }
    }
  }
}

// ---------------------------------------------------------------------------
// GRU scan v9: 8 WGs = 2 dir x 4 row-groups (16 rows), 512 thr (8 waves).
// ALL 3 gates' weights register-resident (192 regs -> AGPRs, scan8 pattern).
// No Wh LDS slab. LDS = h double-buffer only (16 KB). Coalesced packed px
// (3 uint4/thread/step). f32 carry in named scalars. 1 barrier/step.
#define MFMA_B16 __builtin_amdgcn_mfma_f32_16x16x32_bf16

#define GATE1(CT, RI, UZ, UR, UH, AZ, AR, AH, KB)              \
{                                                              \
  f32 zv_ = fsigmoid((AZ)[RI] + bhz##CT + bf2f((ushort)(UZ))); \
  f32 rv_ = fsigmoid((AR)[RI] + bhr##CT + bf2f((ushort)(UR))); \
  f32 hc_ = ftanh(bf2f((ushort)(UH)) + rv_ * ((AH)[RI] + bhh##CT)); \
  f32 hn_ = zv_ * h##CT##RI + (1.f - zv_) * hc_;               \
  h##CT##RI = hn_;                                             \
  *(ushort*)&dst_[(((KB) * 16) + fq * 4 + (RI)) * 16 + e2] = f2bf(hn_); \
}

#define STEP(T, BUF) {                                         \
  const ushort* pt_ = px + (size_t)(T) * 49152;                \
  uint4 q0_ = *(const uint4*)(pt_ + offp);                     \
  uint4 q1_ = *(const uint4*)(pt_ + offp + 4096);              \
  uint4 q2_ = *(const uint4*)(pt_ + offp + 8192);              \
  if ((T) > 0) {                                               \
    uint4 v_ = *(const uint4*)&ldsH[BUF][((ckb * 16) + crow) * 16]; \
    *(uint4*)&hseq[(((size_t)(T) - 1) * 64 + rowbase + crow) * 256 + ckb * 8] = v_; \
  }                                                            \
  f32x4 az0 = {}, az1 = {}, ar0 = {}, ar1 = {}, ah0 = {}, ah1 = {}; \
  _Pragma("unroll")                                            \
  for (int ks = 0; ks < 8; ++ks) {                             \
    short8 a_ = *(const short8*)&ldsH[BUF][((ks * 4 + fq) * 16 + fr) * 16]; \
    az0 = MFMA_B16(a_, wz0[ks], az0, 0, 0, 0);                 \
    ar0 = MFMA_B16(a_, wr0[ks], ar0, 0, 0, 0);                 \
    ah0 = MFMA_B16(a_, wh0[ks], ah0, 0, 0, 0);                 \
    az1 = MFMA_B16(a_, wz1[ks], az1, 0, 0, 0);                 \
    ar1 = MFMA_B16(a_, wr1[ks], ar1, 0, 0, 0);                 \
    ah1 = MFMA_B16(a_, wh1[ks], ah1, 0, 0, 0);                 \
  }                                                            \
  char* dst_ = ldsH[(BUF) ^ 1];                                \
  GATE1(0, 0, q0_.x,       q1_.x,       q2_.x,       az0, ar0, ah0, kb0) \
  GATE1(0, 1, q0_.x >> 16, q1_.x >> 16, q2_.x >> 16, az0, ar0, ah0, kb0) \
  GATE1(0, 2, q0_.y,       q1_.y,       q2_.y,       az0, ar0, ah0, kb0) \
  GATE1(0, 3, q0_.y >> 16, q1_.y >> 16, q2_.y >> 16, az0, ar0, ah0, kb0) \
  GATE1(1, 0, q0_.z,       q1_.z,       q2_.z,       az1, ar1, ah1, kb1) \
  GATE1(1, 1, q0_.z >> 16, q1_.z >> 16, q2_.z >> 16, az1, ar1, ah1, kb1) \
  GATE1(1, 2, q0_.w,       q1_.w,       q2_.w,       az1, ar1, ah1, kb1) \
  GATE1(1, 3, q0_.w >> 16, q1_.w >> 16, q2_.w >> 16, az1, ar1, ah1, kb1) \
  __syncthreads();                                             \
}

__global__ __launch_bounds__(512, 2) void gru_scan9(
    const ushort* __restrict__ pxf, const ushort* __restrict__ pxb,
    const ushort* __restrict__ whtf, const ushort* __restrict__ whtb,
    const f32* __restrict__ b_f, const f32* __restrict__ b_b,
    ushort* __restrict__ hfbf, ushort* __restrict__ hbbf) {
  const int dir = blockIdx.x >> 2;
  const int rg4 = blockIdx.x & 3;
  const int tid = threadIdx.x;
  const int w = tid >> 6, l = tid & 63;
  const int fr = l & 15, fq = l >> 4;
  const ushort* pxd = dir ? pxb : pxf;
  const ushort* wht = dir ? whtb : whtf;
  const f32* bh = (dir ? b_b : b_f) + 768;
  ushort* hseq = dir ? hbbf : hfbf;

  __shared__ __align__(16) char ldsH[2][8192];  // [kblk 0..31][row 0..15][16B]

  if (tid < 512) ((uint4*)ldsH[0])[tid] = make_uint4(0, 0, 0, 0);

  const int c0 = w * 32 + fr;                 // first owned col
  const int c1 = w * 32 + 16 + fr;            // second owned col
  // all-gate weight fragments -> registers (192 regs; land in AGPRs)
  short8 wz0[8], wz1[8], wr0[8], wr1[8], wh0[8], wh1[8];
#pragma unroll
  for (int ks = 0; ks < 8; ++ks) {
    wz0[ks] = *(const short8*)&wht[(size_t)c0 * 256 + ks * 32 + fq * 8];
    wz1[ks] = *(const short8*)&wht[(size_t)c1 * 256 + ks * 32 + fq * 8];
    wr0[ks] = *(const short8*)&wht[(size_t)(256 + c0) * 256 + ks * 32 + fq * 8];
    wr1[ks] = *(const short8*)&wht[(size_t)(256 + c1) * 256 + ks * 32 + fq * 8];
    wh0[ks] = *(const short8*)&wht[(size_t)(512 + c0) * 256 + ks * 32 + fq * 8];
    wh1[ks] = *(const short8*)&wht[(size_t)(512 + c1) * 256 + ks * 32 + fq * 8];
  }
  const f32 bhz0 = bh[c0], bhz1 = bh[c1];
  const f32 bhr0 = bh[256 + c0], bhr1 = bh[256 + c1];
  const f32 bhh0 = bh[512 + c0], bhh1 = bh[512 + c1];
  f32 h00 = 0.f, h01 = 0.f, h02 = 0.f, h03 = 0.f;
  f32 h10 = 0.f, h11 = 0.f, h12 = 0.f, h13 = 0.f;

  // packed px offset (ushort units): [t][rg4][gate][w][fr][fq][ct][ri]
  const ushort* px = pxd + (size_t)rg4 * 12288;
  const int offp = w * 512 + fr * 32 + fq * 8;
  const int rowbase = rg4 * 16;
  const int kb0 = w * 4 + (fr >> 3);          // col c0 k-block
  const int kb1 = kb0 + 2;                    // col c1 k-block
  const int e2 = (fr & 7) * 2;
  // cooperative hseq store assignment (512 thr x 16B = 8KB)
  const int ckb = tid & 31;
  const int crow = tid >> 5;

  __syncthreads();

#pragma unroll 1
  for (int t2 = 0; t2 < TT; t2 += 2) {
    STEP(t2, 0);
    STEP(t2 + 1, 1);
  }
  // tail: hseq[511] = h(512) in ldsH[0]
  {
    uint4 v = *(const uint4*)&ldsH[0][((ckb * 16) + crow) * 16];
    *(uint4*)&hseq[((size_t)511 * 64 + rowbase + crow) * 256 + ckb * 8] = v;
  }
}

// ---------------------------------------------------------------------------
__global__ __launch_bounds__(256) void softmax_ip(ushort* __restrict__ p) {
  size_t row = blockIdx.x;
  uint* pr = (uint*)(p + row * 512);
  int tid = threadIdx.x;
  uint u = pr[tid];
  f32 v0 = bf2f((ushort)(u & 0xffff)), v1 = bf2f((ushort)(u >> 16));
  f32 m = fmaxf(v0, v1);
  for (int off = 32; off; off >>= 1) m = fmaxf(m, __shfl_xor(m, off));
  __shared__ f32 red[4];
  __shared__ f32 red2[4];
  if ((tid & 63) == 0) red[tid >> 6] = m;
  __syncthreads();
  m = fmaxf(fmaxf(red[0], red[1]), fmaxf(red[2], red[3]));
  f32 e0 = __expf(v0 - m), e1 = __expf(v1 - m);
  f32 s = e0 + e1;
  for (int off = 32; off; off >>= 1) s += __shfl_xor(s, off);
  if ((tid & 63) == 0) red2[tid >> 6] = s;
  __syncthreads();
  s = red2[0] + red2[1] + red2[2] + red2[3];
  f32 inv = 1.f / s;
  pr[tid] = (uint)f2bf(e0 * inv) | ((uint)f2bf(e1 * inv) << 16);
}

// ---------------------------------------------------------------------------
__global__ __launch_bounds__(64) void crf_ll_k(
    const f32* __restrict__ logits, const int* __restrict__ y,
    const int* __restrict__ seq_len, const f32* __restrict__ trans,
    f32* __restrict__ out) {
  const int b = blockIdx.x, tid = threadIdx.x;
  __shared__ f32 tr[NN * NN];
  for (int i = tid; i < NN * NN; i += 64) tr[i] = trans[i];
  const f32* em = logits + (size_t)b * TT * NN;
  const int L = seq_len[b];
  const bool act = tid < NN;
  f32 Ecol[NN];
#pragma unroll
  for (int i = 0; i < NN; ++i)
    Ecol[i] = act ? __expf(trans[i * NN + tid]) : 0.f;
  f32 alpha = act ? em[tid] : -1e30f;
  __syncthreads();
  for (int t = 1; t < L; ++t) {
    f32 m = alpha;
    for (int off = 32; off; off >>= 1) m = fmaxf(m, __shfl_xor(m, off));
    f32 e = __expf(alpha - m);
    f32 s = 0.f;
#pragma unroll
    for (int i = 0; i < NN; ++i) s += __shfl(e, i) * Ecol[i];
    if (act) alpha = m + __logf(s) + em[t * NN + tid];
  }
  f32 us = 0.f, ts = 0.f;
  for (int t = tid; t < TT; t += 64) {
    if (t < L) {
      us += em[t * NN + y[b * TT + t]];
      if (t >= 1) ts += tr[y[b * TT + t - 1] * NN + y[b * TT + t]];
    }
  }
  for (int off = 32; off; off >>= 1) { us += __shfl_xor(us, off); ts += __shfl_xor(ts, off); }
  f32 m = alpha;
  for (int off = 32; off; off >>= 1) m = fmaxf(m, __shfl_xor(m, off));
  f32 e = __expf(alpha - m);
  f32 s = e;
  for (int off = 32; off; off >>= 1) s += __shfl_xor(s, off);
  if (tid == 0) out[(size_t)BB * TT + b] = us + ts - (m + __logf(s));
}

__global__ __launch_bounds__(64) void crf_decode_k(
    const f32* __restrict__ logits, const int* __restrict__ seq_len,
    const f32* __restrict__ trans, f32* __restrict__ out) {
  const int b = blockIdx.x, tid = threadIdx.x;
  __shared__ f32 tr[NN][NN];
  __shared__ f32 al[2][NN];
  __shared__ unsigned char bp[TT - 1][NN];
  __shared__ unsigned char pr[TT];
  for (int i = tid; i < NN * NN; i += 64) tr[i / NN][i % NN] = trans[i];
  const f32* em = logits + (size_t)b * TT * NN;
  const int L = seq_len[b];
  if (tid < NN) al[0][tid] = em[tid];
  __syncthreads();
  int cur = 0;
  for (int t = 1; t < TT; ++t) {
    if (tid < NN) {
      if (t < L) {
        f32 m = -1e30f; int arg = 0;
        for (int i = 0; i < NN; ++i) {
          f32 v = al[cur][i] + tr[i][tid];
          if (v > m) { m = v; arg = i; }
        }
        al[cur ^ 1][tid] = m + em[t * NN + tid];
        bp[t - 1][tid] = (unsigned char)arg;
      } else {
        al[cur ^ 1][tid] = al[cur][tid];
        bp[t - 1][tid] = (unsigned char)tid;
      }
    }
    __syncthreads();
    cur ^= 1;
  }
  if (tid == 0) {
    f32 m = -1e30f; int last = 0;
    for (int i = 0; i < NN; ++i)
      if (al[cur][i] > m) { m = al[cur][i]; last = i; }
    int tag = last;
    for (int t = TT - 2; t >= 0; --t) { pr[t + 1] = (unsigned char)tag; tag = bp[t][tag]; }
    pr[0] = (unsigned char)tag;
  }
  __syncthreads();
  for (int t = tid; t < TT; t += 64)
    out[(size_t)b * TT + t] = (f32)pr[t];
}

// ---------------------------------------------------------------------------
extern "C" void kernel_launch(void* const* d_in, const int* in_sizes, int n_in,
                              void* d_out, int out_size, void* d_ws, size_t ws_size,
                              hipStream_t stream) {
  const int* x       = (const int*)d_in[0];
  const int* y       = (const int*)d_in[1];
  const int* seq_len = (const int*)d_in[2];
  const f32* embed   = (const f32*)d_in[3];
  const f32* wx_f    = (const f32*)d_in[4];
  const f32* wh_f    = (const f32*)d_in[5];
  const f32* b_f     = (const f32*)d_in[6];
  const f32* wx_b    = (const f32*)d_in[7];
  const f32* wh_b    = (const f32*)d_in[8];
  const f32* b_b     = (const f32*)d_in[9];
  const f32* wq      = (const f32*)d_in[10];
  const f32* bq      = (const f32*)d_in[11];
  const f32* wk      = (const f32*)d_in[12];
  const f32* bk      = (const f32*)d_in[13];
  const f32* wv      = (const f32*)d_in[14];
  const f32* bv      = (const f32*)d_in[15];
  const f32* wt      = (const f32*)d_in[16];
  const f32* bt      = (const f32*)d_in[17];
  const f32* trans   = (const f32*)d_in[18];
  f32* out = (f32*)d_out;

  char* ws = (char*)d_ws;
  ushort* ebf  = (ushort*)(ws + OFF_EBF);
  ushort* pxfb = (ushort*)(ws + OFF_PXF);
  ushort* pxbb = (ushort*)(ws + OFF_PXB);
  ushort* hfbf = (ushort*)(ws + OFF_HBF_F);
  ushort* hbbf = (ushort*)(ws + OFF_HBF_B);
  ushort* wxtf = (ushort*)(ws + OFF_WXTF);
  ushort* wxtb = (ushort*)(ws + OFF_WXTB);
  ushort* whtf = (ushort*)(ws + OFF_WHTF);
  ushort* whtb = (ushort*)(ws + OFF_WHTB);
  ushort* wqt  = (ushort*)(ws + OFF_WQT);
  ushort* wkt  = (ushort*)(ws + OFF_WKT);
  ushort* wvt  = (ushort*)(ws + OFF_WVT);
  ushort* wtt  = (ushort*)(ws + OFF_WTT);
  ushort* qbf = (ushort*)(ws + OFF_QBF);
  ushort* kbf = (ushort*)(ws + OFF_KBF);
  ushort* vbf = (ushort*)(ws + OFF_VBF);
  ushort* vT  = (ushort*)(ws + OFF_VT);
  ushort* scb = (ushort*)(ws + OFF_SCB);
  ushort* abf = (ushort*)(ws + OFF_ABF);
  f32*    lg  = (f32*)(ws + OFF_LG);

  // ---- setup converts ----
  conv_embed_k<<<8000, 256, 0, stream>>>(embed, ebf, 2048000);
  tconv_k<8><<<768, 256, 0, stream>>>(wx_f, wxtf, 196608, 768);
  tconv_k<8><<<768, 256, 0, stream>>>(wx_b, wxtb, 196608, 768);
  tconv_k<8><<<768, 256, 0, stream>>>(wh_f, whtf, 196608, 768);
  tconv_k<8><<<768, 256, 0, stream>>>(wh_b, whtb, 196608, 768);
  tconv_k<9><<<512, 256, 0, stream>>>(wq, wqt, 131072, 256);
  tconv_k<9><<<512, 256, 0, stream>>>(wk, wkt, 131072, 256);
  tconv_k<9><<<512, 256, 0, stream>>>(wv, wvt, 131072, 256);
  tconv_k<8><<<48, 256, 0, stream>>>(wt, wtt, 12288, 48);

  // ---- px (both dirs, packed layout), then all-registers MFMA scan ----
  mgemm<GM_PX><<<dim3(6, 256), 256, 0, stream>>>(
      ebf, nullptr, wxtf, nullptr, pxfb, b_f, x, 768, 256, 0);
  mgemm<GM_PX><<<dim3(6, 256), 256, 0, stream>>>(
      ebf, nullptr, wxtb, nullptr, pxbb, b_b, x, 768, 256, 1);
  gru_scan9<<<8, 512, 0, stream>>>(pxfb, pxbb, whtf, whtb, b_f, b_b, hfbf, hbbf);

  // ---- attention + logits, single pass over all 64 batches ----
  mgemm<GM_QKV><<<dim3(2, 256), 256, 0, stream>>>(
      hfbf, hbbf, wqt, nullptr, qbf, bq, nullptr, 256, 512, 0);
  mgemm<GM_QKV><<<dim3(2, 256), 256, 0, stream>>>(
      hfbf, hbbf, wkt, nullptr, kbf, bk, nullptr, 256, 512, 0);
  mgemm<GM_QKV><<<dim3(2, 256), 256, 0, stream>>>(
      hfbf, hbbf, wvt, nullptr, vbf, bv, nullptr, 256, 512, 0);
  tr_v_k<<<dim3(16, 8, 64), 256, 0, stream>>>(vbf, vT);
  mgemm<GM_SC><<<dim3(4, 4, 64), 256, 0, stream>>>(
      qbf, nullptr, kbf, nullptr, scb, nullptr, nullptr, 512, 256, 0);
  softmax_ip<<<BB * TT, 256, 0, stream>>>(scb);
  mgemm<GM_AV><<<dim3(2, 4, 64), 256, 0, stream>>>(
      scb, nullptr, vT, nullptr, abf, nullptr, nullptr, 256, 512, 0);
  mgemm<GM_LG><<<dim3(1, 256), 256, 0, stream>>>(
      abf, nullptr, wtt, lg, nullptr, bt, nullptr, 48, 256, 0);

  // ---- CRF ----
  crf_ll_k<<<BB, 64, 0, stream>>>(lg, y, seq_len, trans, out);
  crf_decode_k<<<BB, 64, 0, stream>>>(lg, seq_len, trans, out);
}